// Round 1
// baseline (1682.905 us; speedup 1.0000x reference)
//
#include <hip/hip_runtime.h>
#include <math.h>

#define NNODES 100000

// ---------------- CSR build ----------------

__global__ void count_kernel(const int* __restrict__ dst, int* __restrict__ counts, int E) {
    int e = blockIdx.x * 256 + threadIdx.x;
    if (e < E) atomicAdd(&counts[dst[e]], 1);
}

__global__ void dis_kernel(const int* __restrict__ counts, float* __restrict__ dis, int n) {
    int i = blockIdx.x * 256 + threadIdx.x;
    if (i < n) dis[i] = rsqrtf((float)(counts[i] + 1));  // +1 self-loop, always > 0
}

// exclusive scan of counts -> offs; 1024 elements per block (256 thr x 4)
__global__ void scan_local(const int* __restrict__ counts, int* __restrict__ offs,
                           int* __restrict__ bsums, int n) {
    __shared__ int tsum[256];
    int t = threadIdx.x;
    int base = blockIdx.x * 1024 + t * 4;
    int v0 = (base + 0 < n) ? counts[base + 0] : 0;
    int v1 = (base + 1 < n) ? counts[base + 1] : 0;
    int v2 = (base + 2 < n) ? counts[base + 2] : 0;
    int v3 = (base + 3 < n) ? counts[base + 3] : 0;
    tsum[t] = v0 + v1 + v2 + v3;
    __syncthreads();
    for (int d = 1; d < 256; d <<= 1) {
        int x = tsum[t];
        int y = (t >= d) ? tsum[t - d] : 0;
        __syncthreads();
        tsum[t] = x + y;
        __syncthreads();
    }
    int prev = (t > 0) ? tsum[t - 1] : 0;
    if (base + 0 < n) offs[base + 0] = prev;
    if (base + 1 < n) offs[base + 1] = prev + v0;
    if (base + 2 < n) offs[base + 2] = prev + v0 + v1;
    if (base + 3 < n) offs[base + 3] = prev + v0 + v1 + v2;
    if (t == 255) bsums[blockIdx.x] = tsum[255];
}

__global__ void scan_bsums(int* __restrict__ bsums, int nb) {
    __shared__ int s[128];
    int t = threadIdx.x;
    s[t] = (t < nb) ? bsums[t] : 0;
    __syncthreads();
    for (int d = 1; d < 128; d <<= 1) {
        int x = s[t];
        int y = (t >= d) ? s[t - d] : 0;
        __syncthreads();
        s[t] = x + y;
        __syncthreads();
    }
    int excl = (t > 0) ? s[t - 1] : 0;
    if (t < nb) bsums[t] = excl;
}

__global__ void add_base(int* __restrict__ offs, const int* __restrict__ bsums, int n) {
    int i = blockIdx.x * 256 + threadIdx.x;
    if (i < n) offs[i] += bsums[i >> 10];
}

__global__ void fill_kernel(const int* __restrict__ eidx, const int* __restrict__ offs,
                            int* __restrict__ cursor, const float* __restrict__ dis,
                            int* __restrict__ csrc, float* __restrict__ cnorm, int E) {
    int e = blockIdx.x * 256 + threadIdx.x;
    if (e >= E) return;
    int s = eidx[e];
    int d = eidx[E + e];
    int p = offs[d] + atomicAdd(&cursor[d], 1);
    csrc[p] = s;
    cnorm[p] = dis[s] * dis[d];
}

// ---------------- aggregation: one wave per destination node ----------------
// out[i] = dis[i]^2 * in[i] + sum_e norm[e] * in[src[e]]
template <int F>
__global__ void agg_kernel(const float* __restrict__ in, float* __restrict__ out,
                           const int* __restrict__ offs, const int* __restrict__ counts,
                           const int* __restrict__ csrc, const float* __restrict__ cnorm,
                           const float* __restrict__ dis, int n) {
    int wid = blockIdx.x * (blockDim.x >> 6) + (threadIdx.x >> 6);
    int lane = threadIdx.x & 63;
    if (wid >= n) return;
    float dd = dis[wid];
    float sw = dd * dd;
    const float* row = in + (size_t)wid * F;
    float acc0 = (lane < F) ? sw * row[lane] : 0.f;
    float acc1 = (F > 64) ? sw * row[lane + 64] : 0.f;
    int off = offs[wid], cnt = counts[wid];
    for (int j = 0; j < cnt; ++j) {
        int s = csrc[off + j];
        float nv = cnorm[off + j];
        const float* r2 = in + (size_t)s * F;
        if (lane < F) acc0 += nv * r2[lane];
        if (F > 64) acc1 += nv * r2[lane + 64];
    }
    if (lane < F) out[(size_t)wid * F + lane] = acc0;
    if (F > 64) out[(size_t)wid * F + lane + 64] = acc1;
}

// ---------------- GEMM + bias + activation ----------------
// A: [n, FIN], W: [FIN, FOUT] staged in LDS (cols padded to 128), out: [n, FOUT]
// ACT: 0 = relu, 1 = sigmoid. Each thread: 2 rows x 1 col (one LDS read -> 2 FMA).
template <int FIN, int FOUT, int ACT>
__global__ __launch_bounds__(256) void gemm_act(const float* __restrict__ A,
                                                const float* __restrict__ W,
                                                const float* __restrict__ bias,
                                                float* __restrict__ out, int n) {
    __shared__ float sW[FIN * 128];
    for (int idx = threadIdx.x; idx < FIN * 128; idx += 256) {
        int k = idx >> 7, c = idx & 127;
        sW[idx] = (c < FOUT) ? W[k * FOUT + c] : 0.f;
    }
    __syncthreads();
    int col = threadIdx.x & 127;
    int rsub = threadIdx.x >> 7;  // 0 or 1
    float bv = (col < FOUT) ? bias[col] : 0.f;
    int rend = min((int)((blockIdx.x + 1) * 16), n);
    for (int r = blockIdx.x * 16 + rsub * 2; r < rend; r += 4) {
        const float* ax0 = A + (size_t)r * FIN;
        bool has1 = (r + 1 < rend);
        const float* ax1 = A + (size_t)(has1 ? r + 1 : r) * FIN;
        float acc0 = 0.f, acc1 = 0.f;
#pragma unroll
        for (int k = 0; k < FIN; ++k) {
            float w = sW[(k << 7) + col];
            acc0 = fmaf(ax0[k], w, acc0);
            acc1 = fmaf(ax1[k], w, acc1);
        }
        float v0 = acc0 + bv;
        float v1 = acc1 + bv;
        if (ACT == 0) {
            v0 = fmaxf(v0, 0.f);
            v1 = fmaxf(v1, 0.f);
        } else {
            v0 = 1.f / (1.f + __expf(-v0));
            v1 = 1.f / (1.f + __expf(-v1));
        }
        if (col < FOUT) {
            out[(size_t)r * FOUT + col] = v0;
            if (has1) out[(size_t)(r + 1) * FOUT + col] = v1;
        }
    }
}

extern "C" void kernel_launch(void* const* d_in, const int* in_sizes, int n_in,
                              void* d_out, int out_size, void* d_ws, size_t ws_size,
                              hipStream_t stream) {
    const float* x = (const float*)d_in[0];
    const int* eidx = (const int*)d_in[1];
    const float* W1 = (const float*)d_in[2];
    const float* b1 = (const float*)d_in[3];
    const float* W2 = (const float*)d_in[4];
    const float* b2 = (const float*)d_in[5];
    const float* W3 = (const float*)d_in[6];
    const float* b3 = (const float*)d_in[7];
    const float* W4 = (const float*)d_in[8];
    const float* b4 = (const float*)d_in[9];
    float* out = (float*)d_out;

    const int N = NNODES;
    const int E = in_sizes[1] / 2;

    char* ws = (char*)d_ws;
    size_t off = 0;
    auto alloc = [&](size_t bytes) -> char* {
        char* p = ws + off;
        off = (off + bytes + 255) & ~(size_t)255;
        return p;
    };
    float* dis = (float*)alloc((size_t)N * 4);
    int* counts = (int*)alloc((size_t)N * 4);
    int* offs = (int*)alloc((size_t)N * 4);
    int* cursor = (int*)alloc((size_t)N * 4);
    int* bsums = (int*)alloc(128 * 4);
    int* csrc = (int*)alloc((size_t)E * 4);
    float* cnorm = (float*)alloc((size_t)E * 4);
    float* bufA = (float*)alloc((size_t)N * 128 * 4);
    float* bufB = (float*)alloc((size_t)N * 128 * 4);

    hipMemsetAsync(counts, 0, (size_t)N * 4, stream);
    hipMemsetAsync(cursor, 0, (size_t)N * 4, stream);

    count_kernel<<<(E + 255) / 256, 256, 0, stream>>>(eidx + E, counts, E);
    dis_kernel<<<(N + 255) / 256, 256, 0, stream>>>(counts, dis, N);
    int nb = (N + 1023) / 1024;
    scan_local<<<nb, 256, 0, stream>>>(counts, offs, bsums, N);
    scan_bsums<<<1, 128, 0, stream>>>(bsums, nb);
    add_base<<<(N + 255) / 256, 256, 0, stream>>>(offs, bsums, N);
    fill_kernel<<<(E + 255) / 256, 256, 0, stream>>>(eidx, offs, cursor, dis, csrc, cnorm, E);

    // layer 1: aggregate in 50-dim, then GEMM 50->128 + relu
    agg_kernel<50><<<(N + 3) / 4, 256, 0, stream>>>(x, bufA, offs, counts, csrc, cnorm, dis, N);
    gemm_act<50, 128, 0><<<(N + 15) / 16, 256, 0, stream>>>(bufA, W1, b1, bufB, N);
    // layer 2
    agg_kernel<128><<<(N + 3) / 4, 256, 0, stream>>>(bufB, bufA, offs, counts, csrc, cnorm, dis, N);
    gemm_act<128, 128, 0><<<(N + 15) / 16, 256, 0, stream>>>(bufA, W2, b2, bufB, N);
    // layer 3
    agg_kernel<128><<<(N + 3) / 4, 256, 0, stream>>>(bufB, bufA, offs, counts, csrc, cnorm, dis, N);
    gemm_act<128, 128, 0><<<(N + 15) / 16, 256, 0, stream>>>(bufA, W3, b3, bufB, N);
    // layer 4: aggregate 128, GEMM 128->121 + sigmoid, straight to d_out
    agg_kernel<128><<<(N + 3) / 4, 256, 0, stream>>>(bufB, bufA, offs, counts, csrc, cnorm, dis, N);
    gemm_act<128, 121, 1><<<(N + 15) / 16, 256, 0, stream>>>(bufA, W4, b4, out, N);
}

// Round 2
// 1000.726 us; speedup vs baseline: 1.6817x; 1.6817x over previous
//
#include <hip/hip_runtime.h>
#include <math.h>

#define NNODES 100000

// ---------------- CSR build ----------------

__global__ void count_kernel(const int* __restrict__ dst, int* __restrict__ counts, int E) {
    int e = blockIdx.x * 256 + threadIdx.x;
    if (e < E) atomicAdd(&counts[dst[e]], 1);
}

__global__ void dis_kernel(const int* __restrict__ counts, float* __restrict__ dis, int n) {
    int i = blockIdx.x * 256 + threadIdx.x;
    if (i < n) dis[i] = rsqrtf((float)(counts[i] + 1));  // +1 self-loop, always > 0
}

// exclusive scan of counts -> offs; 1024 elements per block (256 thr x 4)
__global__ void scan_local(const int* __restrict__ counts, int* __restrict__ offs,
                           int* __restrict__ bsums, int n) {
    __shared__ int tsum[256];
    int t = threadIdx.x;
    int base = blockIdx.x * 1024 + t * 4;
    int v0 = (base + 0 < n) ? counts[base + 0] : 0;
    int v1 = (base + 1 < n) ? counts[base + 1] : 0;
    int v2 = (base + 2 < n) ? counts[base + 2] : 0;
    int v3 = (base + 3 < n) ? counts[base + 3] : 0;
    tsum[t] = v0 + v1 + v2 + v3;
    __syncthreads();
    for (int d = 1; d < 256; d <<= 1) {
        int x = tsum[t];
        int y = (t >= d) ? tsum[t - d] : 0;
        __syncthreads();
        tsum[t] = x + y;
        __syncthreads();
    }
    int prev = (t > 0) ? tsum[t - 1] : 0;
    if (base + 0 < n) offs[base + 0] = prev;
    if (base + 1 < n) offs[base + 1] = prev + v0;
    if (base + 2 < n) offs[base + 2] = prev + v0 + v1;
    if (base + 3 < n) offs[base + 3] = prev + v0 + v1 + v2;
    if (t == 255) bsums[blockIdx.x] = tsum[255];
}

__global__ void scan_bsums(int* __restrict__ bsums, int nb) {
    __shared__ int s[128];
    int t = threadIdx.x;
    s[t] = (t < nb) ? bsums[t] : 0;
    __syncthreads();
    for (int d = 1; d < 128; d <<= 1) {
        int x = s[t];
        int y = (t >= d) ? s[t - d] : 0;
        __syncthreads();
        s[t] = x + y;
        __syncthreads();
    }
    int excl = (t > 0) ? s[t - 1] : 0;
    if (t < nb) bsums[t] = excl;
}

__global__ void add_base(int* __restrict__ offs, const int* __restrict__ bsums, int n) {
    int i = blockIdx.x * 256 + threadIdx.x;
    if (i < n) offs[i] += bsums[i >> 10];
}

__global__ void fill_kernel(const int* __restrict__ eidx, const int* __restrict__ offs,
                            int* __restrict__ cursor, const float* __restrict__ dis,
                            int* __restrict__ csrc, float* __restrict__ cnorm, int E) {
    int e = blockIdx.x * 256 + threadIdx.x;
    if (e >= E) return;
    int s = eidx[e];
    int d = eidx[E + e];
    int p = offs[d] + atomicAdd(&cursor[d], 1);
    csrc[p] = s;
    cnorm[p] = dis[s] * dis[d];
}

// ---------------- aggregation: one wave per destination node ----------------
// out[i] = dis[i]^2 * in[i] + sum_e norm[e] * in[src[e]]
template <int F>
__global__ void agg_kernel(const float* __restrict__ in, float* __restrict__ out,
                           const int* __restrict__ offs, const int* __restrict__ counts,
                           const int* __restrict__ csrc, const float* __restrict__ cnorm,
                           const float* __restrict__ dis, int n) {
    int wid = blockIdx.x * (blockDim.x >> 6) + (threadIdx.x >> 6);
    int lane = threadIdx.x & 63;
    if (wid >= n) return;
    float dd = dis[wid];
    float sw = dd * dd;
    const float* row = in + (size_t)wid * F;
    float acc0 = (lane < F) ? sw * row[lane] : 0.f;
    float acc1 = (F > 64) ? sw * row[lane + 64] : 0.f;
    int off = offs[wid], cnt = counts[wid];
    for (int j = 0; j < cnt; ++j) {
        int s = csrc[off + j];
        float nv = cnorm[off + j];
        const float* r2 = in + (size_t)s * F;
        if (lane < F) acc0 += nv * r2[lane];
        if (F > 64) acc1 += nv * r2[lane + 64];
    }
    if (lane < F) out[(size_t)wid * F + lane] = acc0;
    if (F > 64) out[(size_t)wid * F + lane + 64] = acc1;
}

// ---------------- tiled SGEMM + bias + activation ----------------
// Block tile: 64 rows x 128 cols, K-step 32. Thread tile: 8 rows x 4 cols.
// A staged TRANSPOSED in LDS (sAT[k][row]) so per-k A-fragment = 2x ds_read_b128.
// ACT: 0 = relu, 1 = sigmoid.
template <int FIN, int FOUT, int ACT>
__global__ __launch_bounds__(256) void gemm_act(const float* __restrict__ A,
                                                const float* __restrict__ W,
                                                const float* __restrict__ bias,
                                                float* __restrict__ out, int n) {
    constexpr int KS = 32;
    constexpr int NKC = (FIN + KS - 1) / KS;
    __shared__ __align__(16) float sAT[KS][68];   // [k][row], stride 68 (16B-aligned rows)
    __shared__ __align__(16) float sW[KS][128];

    const int tid = threadIdx.x;
    const int tx = tid & 31;    // col group: cols tx*4 .. tx*4+3
    const int ty = tid >> 5;    // row group: rows ty*8 .. ty*8+7
    const int rbase = blockIdx.x * 64;

    float acc[8][4];
#pragma unroll
    for (int r = 0; r < 8; ++r)
#pragma unroll
        for (int c = 0; c < 4; ++c) acc[r][c] = 0.f;

    for (int kc = 0; kc < NKC; ++kc) {
        // ---- stage A tile transposed: rows tid>>3 (+32), k-quad (tid&7)*4 ----
        {
            int row = tid >> 3;
            int kq = (tid & 7) * 4;
#pragma unroll
            for (int p = 0; p < 2; ++p, row += 32) {
                int gr = rbase + row;
                float v[4];
                if constexpr (FIN % 4 == 0) {
                    if (gr < n && kc * KS + kq + 3 < FIN) {
                        float4 t4 = *(const float4*)&A[(size_t)gr * FIN + kc * KS + kq];
                        v[0] = t4.x; v[1] = t4.y; v[2] = t4.z; v[3] = t4.w;
                    } else {
#pragma unroll
                        for (int i = 0; i < 4; ++i) {
                            int gk = kc * KS + kq + i;
                            v[i] = (gr < n && gk < FIN) ? A[(size_t)gr * FIN + gk] : 0.f;
                        }
                    }
                } else {
#pragma unroll
                    for (int i = 0; i < 4; ++i) {
                        int gk = kc * KS + kq + i;
                        v[i] = (gr < n && gk < FIN) ? A[(size_t)gr * FIN + gk] : 0.f;
                    }
                }
#pragma unroll
                for (int i = 0; i < 4; ++i) sAT[kq + i][row] = v[i];
            }
        }
        // ---- stage W tile: sW[kr][c], thread: c4=(tid&31)*4, kr=tid>>5 step 8 ----
        {
            int c4 = (tid & 31) * 4;
            int kr = tid >> 5;
#pragma unroll
            for (int p = 0; p < 4; ++p, kr += 8) {
                int gk = kc * KS + kr;
                float v[4];
                if constexpr (FOUT % 4 == 0) {
                    if (gk < FIN) {
                        float4 t4 = *(const float4*)&W[(size_t)gk * FOUT + c4];
                        v[0] = t4.x; v[1] = t4.y; v[2] = t4.z; v[3] = t4.w;
                    } else {
                        v[0] = v[1] = v[2] = v[3] = 0.f;
                    }
                } else {
#pragma unroll
                    for (int i = 0; i < 4; ++i)
                        v[i] = (gk < FIN && c4 + i < FOUT) ? W[(size_t)gk * FOUT + c4 + i] : 0.f;
                }
                *(float4*)&sW[kr][c4] = *(float4*)v;
            }
        }
        __syncthreads();

#pragma unroll
        for (int k = 0; k < KS; ++k) {
            float4 wv = *(const float4*)&sW[k][tx * 4];
            float4 a0 = *(const float4*)&sAT[k][ty * 8];
            float4 a1 = *(const float4*)&sAT[k][ty * 8 + 4];
            const float ar[8] = {a0.x, a0.y, a0.z, a0.w, a1.x, a1.y, a1.z, a1.w};
            const float wc[4] = {wv.x, wv.y, wv.z, wv.w};
#pragma unroll
            for (int r = 0; r < 8; ++r)
#pragma unroll
                for (int c = 0; c < 4; ++c)
                    acc[r][c] = fmaf(ar[r], wc[c], acc[r][c]);
        }
        __syncthreads();
    }

    // ---- epilogue: bias + activation + store ----
    float bv[4];
#pragma unroll
    for (int c = 0; c < 4; ++c)
        bv[c] = (tx * 4 + c < FOUT) ? bias[tx * 4 + c] : 0.f;

#pragma unroll
    for (int r = 0; r < 8; ++r) {
        int gr = rbase + ty * 8 + r;
        if (gr >= n) continue;
        float v[4];
#pragma unroll
        for (int c = 0; c < 4; ++c) {
            float t = acc[r][c] + bv[c];
            if (ACT == 0) t = fmaxf(t, 0.f);
            else t = 1.f / (1.f + __expf(-t));
            v[c] = t;
        }
        if constexpr (FOUT % 4 == 0) {
            *(float4*)&out[(size_t)gr * FOUT + tx * 4] = *(float4*)v;
        } else {
#pragma unroll
            for (int c = 0; c < 4; ++c)
                if (tx * 4 + c < FOUT) out[(size_t)gr * FOUT + tx * 4 + c] = v[c];
        }
    }
}

extern "C" void kernel_launch(void* const* d_in, const int* in_sizes, int n_in,
                              void* d_out, int out_size, void* d_ws, size_t ws_size,
                              hipStream_t stream) {
    const float* x = (const float*)d_in[0];
    const int* eidx = (const int*)d_in[1];
    const float* W1 = (const float*)d_in[2];
    const float* b1 = (const float*)d_in[3];
    const float* W2 = (const float*)d_in[4];
    const float* b2 = (const float*)d_in[5];
    const float* W3 = (const float*)d_in[6];
    const float* b3 = (const float*)d_in[7];
    const float* W4 = (const float*)d_in[8];
    const float* b4 = (const float*)d_in[9];
    float* out = (float*)d_out;

    const int N = NNODES;
    const int E = in_sizes[1] / 2;

    char* ws = (char*)d_ws;
    size_t off = 0;
    auto alloc = [&](size_t bytes) -> char* {
        char* p = ws + off;
        off = (off + bytes + 255) & ~(size_t)255;
        return p;
    };
    float* dis = (float*)alloc((size_t)N * 4);
    int* counts = (int*)alloc((size_t)N * 4);
    int* offs = (int*)alloc((size_t)N * 4);
    int* cursor = (int*)alloc((size_t)N * 4);
    int* bsums = (int*)alloc(128 * 4);
    int* csrc = (int*)alloc((size_t)E * 4);
    float* cnorm = (float*)alloc((size_t)E * 4);
    float* bufA = (float*)alloc((size_t)N * 128 * 4);
    float* bufB = (float*)alloc((size_t)N * 128 * 4);

    hipMemsetAsync(counts, 0, (size_t)N * 4, stream);
    hipMemsetAsync(cursor, 0, (size_t)N * 4, stream);

    count_kernel<<<(E + 255) / 256, 256, 0, stream>>>(eidx + E, counts, E);
    dis_kernel<<<(N + 255) / 256, 256, 0, stream>>>(counts, dis, N);
    int nb = (N + 1023) / 1024;
    scan_local<<<nb, 256, 0, stream>>>(counts, offs, bsums, N);
    scan_bsums<<<1, 128, 0, stream>>>(bsums, nb);
    add_base<<<(N + 255) / 256, 256, 0, stream>>>(offs, bsums, N);
    fill_kernel<<<(E + 255) / 256, 256, 0, stream>>>(eidx, offs, cursor, dis, csrc, cnorm, E);

    // layer 1: aggregate in 50-dim, then GEMM 50->128 + relu
    agg_kernel<50><<<(N + 3) / 4, 256, 0, stream>>>(x, bufA, offs, counts, csrc, cnorm, dis, N);
    gemm_act<50, 128, 0><<<(N + 63) / 64, 256, 0, stream>>>(bufA, W1, b1, bufB, N);
    // layer 2
    agg_kernel<128><<<(N + 3) / 4, 256, 0, stream>>>(bufB, bufA, offs, counts, csrc, cnorm, dis, N);
    gemm_act<128, 128, 0><<<(N + 63) / 64, 256, 0, stream>>>(bufA, W2, b2, bufB, N);
    // layer 3
    agg_kernel<128><<<(N + 3) / 4, 256, 0, stream>>>(bufB, bufA, offs, counts, csrc, cnorm, dis, N);
    gemm_act<128, 128, 0><<<(N + 63) / 64, 256, 0, stream>>>(bufA, W3, b3, bufB, N);
    // layer 4: aggregate 128, GEMM 128->121 + sigmoid, straight to d_out
    agg_kernel<128><<<(N + 3) / 4, 256, 0, stream>>>(bufB, bufA, offs, counts, csrc, cnorm, dis, N);
    gemm_act<128, 121, 1><<<(N + 63) / 64, 256, 0, stream>>>(bufA, W4, b4, out, N);
}

// Round 3
// 786.183 us; speedup vs baseline: 2.1406x; 1.2729x over previous
//
#include <hip/hip_runtime.h>
#include <math.h>

#define NNODES 100000

// ---------------- CSR build (segments padded to multiple of 8) ----------------

__global__ void count_kernel(const int* __restrict__ dst, int* __restrict__ counts, int E) {
    int e = blockIdx.x * 256 + threadIdx.x;
    if (e < E) atomicAdd(&counts[dst[e]], 1);
}

__global__ void dis_kernel(const int* __restrict__ counts, float* __restrict__ dis, int n) {
    int i = blockIdx.x * 256 + threadIdx.x;
    if (i < n) dis[i] = rsqrtf((float)(counts[i] + 1));  // +1 self-loop, always > 0
}

// exclusive scan of PADDED counts -> offs; 1024 elements per block (256 thr x 4)
__global__ void scan_local(const int* __restrict__ counts, int* __restrict__ offs,
                           int* __restrict__ bsums, int n) {
    __shared__ int tsum[256];
    int t = threadIdx.x;
    int base = blockIdx.x * 1024 + t * 4;
    int v0 = (base + 0 < n) ? ((counts[base + 0] + 7) & ~7) : 0;
    int v1 = (base + 1 < n) ? ((counts[base + 1] + 7) & ~7) : 0;
    int v2 = (base + 2 < n) ? ((counts[base + 2] + 7) & ~7) : 0;
    int v3 = (base + 3 < n) ? ((counts[base + 3] + 7) & ~7) : 0;
    tsum[t] = v0 + v1 + v2 + v3;
    __syncthreads();
    for (int d = 1; d < 256; d <<= 1) {
        int x = tsum[t];
        int y = (t >= d) ? tsum[t - d] : 0;
        __syncthreads();
        tsum[t] = x + y;
        __syncthreads();
    }
    int prev = (t > 0) ? tsum[t - 1] : 0;
    if (base + 0 < n) offs[base + 0] = prev;
    if (base + 1 < n) offs[base + 1] = prev + v0;
    if (base + 2 < n) offs[base + 2] = prev + v0 + v1;
    if (base + 3 < n) offs[base + 3] = prev + v0 + v1 + v2;
    if (t == 255) bsums[blockIdx.x] = tsum[255];
}

__global__ void scan_bsums(int* __restrict__ bsums, int nb) {
    __shared__ int s[128];
    int t = threadIdx.x;
    s[t] = (t < nb) ? bsums[t] : 0;
    __syncthreads();
    for (int d = 1; d < 128; d <<= 1) {
        int x = s[t];
        int y = (t >= d) ? s[t - d] : 0;
        __syncthreads();
        s[t] = x + y;
        __syncthreads();
    }
    int excl = (t > 0) ? s[t - 1] : 0;
    if (t < nb) bsums[t] = excl;
}

__global__ void add_base(int* __restrict__ offs, const int* __restrict__ bsums, int n) {
    int i = blockIdx.x * 256 + threadIdx.x;
    if (i < n) offs[i] += bsums[i >> 10];
}

__global__ void fill_kernel(const int* __restrict__ eidx, const int* __restrict__ offs,
                            int* __restrict__ cursor, const float* __restrict__ dis,
                            int* __restrict__ csrc, float* __restrict__ cnorm, int E) {
    int e = blockIdx.x * 256 + threadIdx.x;
    if (e >= E) return;
    int s = eidx[e];
    int d = eidx[E + e];
    int p = offs[d] + atomicAdd(&cursor[d], 1);
    csrc[p] = s;
    cnorm[p] = dis[s] * dis[d];
}

// ---------------- aggregation: one wave per destination node ----------------
// out[i] = dis[i]^2 * in[i] + sum_e norm[e] * in[src[e]]
// Segments padded to x8 with (src=0, norm=0); csrc/cnorm pre-zeroed so pad
// addresses are valid and pad contributions are exactly 0.

__global__ __launch_bounds__(256) void agg128_kernel(
        const float* __restrict__ in, float* __restrict__ out,
        const int* __restrict__ offs, const int* __restrict__ counts,
        const int* __restrict__ csrc, const float* __restrict__ cnorm,
        const float* __restrict__ dis, int n) {
    int wid = blockIdx.x * (blockDim.x >> 6) + (threadIdx.x >> 6);
    int lane = threadIdx.x & 63;
    if (wid >= n) return;
    const float2* __restrict__ in2 = (const float2*)in;
    float dd = dis[wid];
    float2 self = in2[(size_t)wid * 64 + lane];
    float a0 = dd * dd * self.x;
    float a1 = dd * dd * self.y;
    int off = offs[wid];
    int pcnt = (counts[wid] + 7) & ~7;
    for (int j = 0; j < pcnt; j += 8) {
        int4 s0 = *(const int4*)&csrc[off + j];
        int4 s1 = *(const int4*)&csrc[off + j + 4];
        float4 n0 = *(const float4*)&cnorm[off + j];
        float4 n1 = *(const float4*)&cnorm[off + j + 4];
        float2 r0 = in2[(size_t)s0.x * 64 + lane];
        float2 r1 = in2[(size_t)s0.y * 64 + lane];
        float2 r2 = in2[(size_t)s0.z * 64 + lane];
        float2 r3 = in2[(size_t)s0.w * 64 + lane];
        float2 r4 = in2[(size_t)s1.x * 64 + lane];
        float2 r5 = in2[(size_t)s1.y * 64 + lane];
        float2 r6 = in2[(size_t)s1.z * 64 + lane];
        float2 r7 = in2[(size_t)s1.w * 64 + lane];
        a0 = fmaf(n0.x, r0.x, a0); a1 = fmaf(n0.x, r0.y, a1);
        a0 = fmaf(n0.y, r1.x, a0); a1 = fmaf(n0.y, r1.y, a1);
        a0 = fmaf(n0.z, r2.x, a0); a1 = fmaf(n0.z, r2.y, a1);
        a0 = fmaf(n0.w, r3.x, a0); a1 = fmaf(n0.w, r3.y, a1);
        a0 = fmaf(n1.x, r4.x, a0); a1 = fmaf(n1.x, r4.y, a1);
        a0 = fmaf(n1.y, r5.x, a0); a1 = fmaf(n1.y, r5.y, a1);
        a0 = fmaf(n1.z, r6.x, a0); a1 = fmaf(n1.z, r6.y, a1);
        a0 = fmaf(n1.w, r7.x, a0); a1 = fmaf(n1.w, r7.y, a1);
    }
    ((float2*)out)[(size_t)wid * 64 + lane] = make_float2(a0, a1);
}

__global__ __launch_bounds__(256) void agg50_kernel(
        const float* __restrict__ in, float* __restrict__ out,
        const int* __restrict__ offs, const int* __restrict__ counts,
        const int* __restrict__ csrc, const float* __restrict__ cnorm,
        const float* __restrict__ dis, int n) {
    int wid = blockIdx.x * (blockDim.x >> 6) + (threadIdx.x >> 6);
    int lane = threadIdx.x & 63;
    if (wid >= n) return;
    float dd = dis[wid];
    float acc = 0.f;
    if (lane < 50) acc = dd * dd * in[(size_t)wid * 50 + lane];
    int off = offs[wid];
    int pcnt = (counts[wid] + 7) & ~7;
    for (int j = 0; j < pcnt; j += 8) {
        int4 s0 = *(const int4*)&csrc[off + j];
        int4 s1 = *(const int4*)&csrc[off + j + 4];
        float4 n0 = *(const float4*)&cnorm[off + j];
        float4 n1 = *(const float4*)&cnorm[off + j + 4];
        if (lane < 50) {
            float r0 = in[(size_t)s0.x * 50 + lane];
            float r1 = in[(size_t)s0.y * 50 + lane];
            float r2 = in[(size_t)s0.z * 50 + lane];
            float r3 = in[(size_t)s0.w * 50 + lane];
            float r4 = in[(size_t)s1.x * 50 + lane];
            float r5 = in[(size_t)s1.y * 50 + lane];
            float r6 = in[(size_t)s1.z * 50 + lane];
            float r7 = in[(size_t)s1.w * 50 + lane];
            acc = fmaf(n0.x, r0, acc);
            acc = fmaf(n0.y, r1, acc);
            acc = fmaf(n0.z, r2, acc);
            acc = fmaf(n0.w, r3, acc);
            acc = fmaf(n1.x, r4, acc);
            acc = fmaf(n1.y, r5, acc);
            acc = fmaf(n1.z, r6, acc);
            acc = fmaf(n1.w, r7, acc);
        }
    }
    if (lane < 50) out[(size_t)wid * 50 + lane] = acc;
}

// ---------------- tiled SGEMM + bias + activation ----------------
// Block tile: 64 rows x 128 cols, K-step 32. Thread tile: 8 rows x 4 cols.
// A staged TRANSPOSED in LDS (sAT[k][row]) so per-k A-fragment = 2x ds_read_b128.
// ACT: 0 = relu, 1 = sigmoid.
template <int FIN, int FOUT, int ACT>
__global__ __launch_bounds__(256) void gemm_act(const float* __restrict__ A,
                                                const float* __restrict__ W,
                                                const float* __restrict__ bias,
                                                float* __restrict__ out, int n) {
    constexpr int KS = 32;
    constexpr int NKC = (FIN + KS - 1) / KS;
    __shared__ __align__(16) float sAT[KS][68];   // [k][row], stride 68 (16B-aligned rows)
    __shared__ __align__(16) float sW[KS][128];

    const int tid = threadIdx.x;
    const int tx = tid & 31;    // col group: cols tx*4 .. tx*4+3
    const int ty = tid >> 5;    // row group: rows ty*8 .. ty*8+7
    const int rbase = blockIdx.x * 64;

    float acc[8][4];
#pragma unroll
    for (int r = 0; r < 8; ++r)
#pragma unroll
        for (int c = 0; c < 4; ++c) acc[r][c] = 0.f;

    for (int kc = 0; kc < NKC; ++kc) {
        // ---- stage A tile transposed: rows tid>>3 (+32), k-quad (tid&7)*4 ----
        {
            int row = tid >> 3;
            int kq = (tid & 7) * 4;
#pragma unroll
            for (int p = 0; p < 2; ++p, row += 32) {
                int gr = rbase + row;
                float v[4];
                if constexpr (FIN % 4 == 0) {
                    if (gr < n && kc * KS + kq + 3 < FIN) {
                        float4 t4 = *(const float4*)&A[(size_t)gr * FIN + kc * KS + kq];
                        v[0] = t4.x; v[1] = t4.y; v[2] = t4.z; v[3] = t4.w;
                    } else {
#pragma unroll
                        for (int i = 0; i < 4; ++i) {
                            int gk = kc * KS + kq + i;
                            v[i] = (gr < n && gk < FIN) ? A[(size_t)gr * FIN + gk] : 0.f;
                        }
                    }
                } else {
#pragma unroll
                    for (int i = 0; i < 4; ++i) {
                        int gk = kc * KS + kq + i;
                        v[i] = (gr < n && gk < FIN) ? A[(size_t)gr * FIN + gk] : 0.f;
                    }
                }
#pragma unroll
                for (int i = 0; i < 4; ++i) sAT[kq + i][row] = v[i];
            }
        }
        // ---- stage W tile: sW[kr][c], thread: c4=(tid&31)*4, kr=tid>>5 step 8 ----
        {
            int c4 = (tid & 31) * 4;
            int kr = tid >> 5;
#pragma unroll
            for (int p = 0; p < 4; ++p, kr += 8) {
                int gk = kc * KS + kr;
                float v[4];
                if constexpr (FOUT % 4 == 0) {
                    if (gk < FIN) {
                        float4 t4 = *(const float4*)&W[(size_t)gk * FOUT + c4];
                        v[0] = t4.x; v[1] = t4.y; v[2] = t4.z; v[3] = t4.w;
                    } else {
                        v[0] = v[1] = v[2] = v[3] = 0.f;
                    }
                } else {
#pragma unroll
                    for (int i = 0; i < 4; ++i)
                        v[i] = (gk < FIN && c4 + i < FOUT) ? W[(size_t)gk * FOUT + c4 + i] : 0.f;
                }
                *(float4*)&sW[kr][c4] = *(float4*)v;
            }
        }
        __syncthreads();

#pragma unroll
        for (int k = 0; k < KS; ++k) {
            float4 wv = *(const float4*)&sW[k][tx * 4];
            float4 a0 = *(const float4*)&sAT[k][ty * 8];
            float4 a1 = *(const float4*)&sAT[k][ty * 8 + 4];
            const float ar[8] = {a0.x, a0.y, a0.z, a0.w, a1.x, a1.y, a1.z, a1.w};
            const float wc[4] = {wv.x, wv.y, wv.z, wv.w};
#pragma unroll
            for (int r = 0; r < 8; ++r)
#pragma unroll
                for (int c = 0; c < 4; ++c)
                    acc[r][c] = fmaf(ar[r], wc[c], acc[r][c]);
        }
        __syncthreads();
    }

    // ---- epilogue: bias + activation + store ----
    float bv[4];
#pragma unroll
    for (int c = 0; c < 4; ++c)
        bv[c] = (tx * 4 + c < FOUT) ? bias[tx * 4 + c] : 0.f;

#pragma unroll
    for (int r = 0; r < 8; ++r) {
        int gr = rbase + ty * 8 + r;
        if (gr >= n) continue;
        float v[4];
#pragma unroll
        for (int c = 0; c < 4; ++c) {
            float t = acc[r][c] + bv[c];
            if (ACT == 0) t = fmaxf(t, 0.f);
            else t = 1.f / (1.f + __expf(-t));
            v[c] = t;
        }
        if constexpr (FOUT % 4 == 0) {
            *(float4*)&out[(size_t)gr * FOUT + tx * 4] = *(float4*)v;
        } else {
#pragma unroll
            for (int c = 0; c < 4; ++c)
                if (tx * 4 + c < FOUT) out[(size_t)gr * FOUT + tx * 4 + c] = v[c];
        }
    }
}

extern "C" void kernel_launch(void* const* d_in, const int* in_sizes, int n_in,
                              void* d_out, int out_size, void* d_ws, size_t ws_size,
                              hipStream_t stream) {
    const float* x = (const float*)d_in[0];
    const int* eidx = (const int*)d_in[1];
    const float* W1 = (const float*)d_in[2];
    const float* b1 = (const float*)d_in[3];
    const float* W2 = (const float*)d_in[4];
    const float* b2 = (const float*)d_in[5];
    const float* W3 = (const float*)d_in[6];
    const float* b3 = (const float*)d_in[7];
    const float* W4 = (const float*)d_in[8];
    const float* b4 = (const float*)d_in[9];
    float* out = (float*)d_out;

    const int N = NNODES;
    const int E = in_sizes[1] / 2;
    const size_t PE = (size_t)E + 8u * N;  // padded edge-array capacity

    char* ws = (char*)d_ws;
    size_t off = 0;
    auto alloc = [&](size_t bytes) -> char* {
        char* p = ws + off;
        off = (off + bytes + 255) & ~(size_t)255;
        return p;
    };
    float* dis = (float*)alloc((size_t)N * 4);
    int* counts = (int*)alloc((size_t)N * 4);
    int* offs = (int*)alloc((size_t)N * 4);
    int* cursor = (int*)alloc((size_t)N * 4);
    int* bsums = (int*)alloc(128 * 4);
    int* csrc = (int*)alloc(PE * 4);
    float* cnorm = (float*)alloc(PE * 4);
    float* bufA = (float*)alloc((size_t)N * 128 * 4);
    float* bufB = (float*)alloc((size_t)N * 128 * 4);

    hipMemsetAsync(counts, 0, (size_t)N * 4, stream);
    hipMemsetAsync(cursor, 0, (size_t)N * 4, stream);
    hipMemsetAsync(csrc, 0, PE * 4, stream);   // pad src -> node 0 (valid addr)
    hipMemsetAsync(cnorm, 0, PE * 4, stream);  // pad norm -> 0 contribution

    count_kernel<<<(E + 255) / 256, 256, 0, stream>>>(eidx + E, counts, E);
    dis_kernel<<<(N + 255) / 256, 256, 0, stream>>>(counts, dis, N);
    int nb = (N + 1023) / 1024;
    scan_local<<<nb, 256, 0, stream>>>(counts, offs, bsums, N);
    scan_bsums<<<1, 128, 0, stream>>>(bsums, nb);
    add_base<<<(N + 255) / 256, 256, 0, stream>>>(offs, bsums, N);
    fill_kernel<<<(E + 255) / 256, 256, 0, stream>>>(eidx, offs, cursor, dis, csrc, cnorm, E);

    // layer 1: aggregate in 50-dim, then GEMM 50->128 + relu
    agg50_kernel<<<(N + 3) / 4, 256, 0, stream>>>(x, bufA, offs, counts, csrc, cnorm, dis, N);
    gemm_act<50, 128, 0><<<(N + 63) / 64, 256, 0, stream>>>(bufA, W1, b1, bufB, N);
    // layer 2
    agg128_kernel<<<(N + 3) / 4, 256, 0, stream>>>(bufB, bufA, offs, counts, csrc, cnorm, dis, N);
    gemm_act<128, 128, 0><<<(N + 63) / 64, 256, 0, stream>>>(bufA, W2, b2, bufB, N);
    // layer 3
    agg128_kernel<<<(N + 3) / 4, 256, 0, stream>>>(bufB, bufA, offs, counts, csrc, cnorm, dis, N);
    gemm_act<128, 128, 0><<<(N + 63) / 64, 256, 0, stream>>>(bufA, W3, b3, bufB, N);
    // layer 4: aggregate 128, GEMM 128->121 + sigmoid, straight to d_out
    agg128_kernel<<<(N + 3) / 4, 256, 0, stream>>>(bufB, bufA, offs, counts, csrc, cnorm, dis, N);
    gemm_act<128, 121, 1><<<(N + 63) / 64, 256, 0, stream>>>(bufA, W4, b4, out, N);
}

// Round 4
// 611.911 us; speedup vs baseline: 2.7502x; 1.2848x over previous
//
#include <hip/hip_runtime.h>
#include <hip/hip_fp16.h>
#include <math.h>

#define NNODES 100000

// ---------------- CSR build (segments padded to multiple of 8) ----------------

__global__ void count_kernel(const int* __restrict__ dst, int* __restrict__ counts, int E) {
    int e = blockIdx.x * 256 + threadIdx.x;
    if (e < E) atomicAdd(&counts[dst[e]], 1);
}

__global__ void dis_kernel(const int* __restrict__ counts, float* __restrict__ dis, int n) {
    int i = blockIdx.x * 256 + threadIdx.x;
    if (i < n) dis[i] = rsqrtf((float)(counts[i] + 1));  // +1 self-loop, always > 0
}

// exclusive scan of PADDED counts -> offs; 1024 elements per block (256 thr x 4)
__global__ void scan_local(const int* __restrict__ counts, int* __restrict__ offs,
                           int* __restrict__ bsums, int n) {
    __shared__ int tsum[256];
    int t = threadIdx.x;
    int base = blockIdx.x * 1024 + t * 4;
    int v0 = (base + 0 < n) ? ((counts[base + 0] + 7) & ~7) : 0;
    int v1 = (base + 1 < n) ? ((counts[base + 1] + 7) & ~7) : 0;
    int v2 = (base + 2 < n) ? ((counts[base + 2] + 7) & ~7) : 0;
    int v3 = (base + 3 < n) ? ((counts[base + 3] + 7) & ~7) : 0;
    tsum[t] = v0 + v1 + v2 + v3;
    __syncthreads();
    for (int d = 1; d < 256; d <<= 1) {
        int x = tsum[t];
        int y = (t >= d) ? tsum[t - d] : 0;
        __syncthreads();
        tsum[t] = x + y;
        __syncthreads();
    }
    int prev = (t > 0) ? tsum[t - 1] : 0;
    if (base + 0 < n) offs[base + 0] = prev;
    if (base + 1 < n) offs[base + 1] = prev + v0;
    if (base + 2 < n) offs[base + 2] = prev + v0 + v1;
    if (base + 3 < n) offs[base + 3] = prev + v0 + v1 + v2;
    if (t == 255) bsums[blockIdx.x] = tsum[255];
}

__global__ void scan_bsums(int* __restrict__ bsums, int nb) {
    __shared__ int s[128];
    int t = threadIdx.x;
    s[t] = (t < nb) ? bsums[t] : 0;
    __syncthreads();
    for (int d = 1; d < 128; d <<= 1) {
        int x = s[t];
        int y = (t >= d) ? s[t - d] : 0;
        __syncthreads();
        s[t] = x + y;
        __syncthreads();
    }
    int excl = (t > 0) ? s[t - 1] : 0;
    if (t < nb) bsums[t] = excl;
}

__global__ void add_base(int* __restrict__ offs, const int* __restrict__ bsums, int n) {
    int i = blockIdx.x * 256 + threadIdx.x;
    if (i < n) offs[i] += bsums[i >> 10];
}

__global__ void fill_kernel(const int* __restrict__ eidx, const int* __restrict__ offs,
                            int* __restrict__ cursor, const float* __restrict__ dis,
                            int* __restrict__ csrc, float* __restrict__ cnorm, int E) {
    int e = blockIdx.x * 256 + threadIdx.x;
    if (e >= E) return;
    int s = eidx[e];
    int d = eidx[E + e];
    int p = offs[d] + atomicAdd(&cursor[d], 1);
    csrc[p] = s;
    cnorm[p] = dis[s] * dis[d];
}

// fp32 -> fp16 cast (2 elements per thread)
__global__ void cast_kernel(const float* __restrict__ src, __half* __restrict__ dst, int n2) {
    int i = blockIdx.x * 256 + threadIdx.x;
    if (i < n2) {
        float2 v = *(const float2*)&src[i * 2];
        __half2 h = __floats2half2_rn(v.x, v.y);
        *(__half2*)&dst[i * 2] = h;
    }
}

// ---------------- aggregation: one wave per destination node ----------------
// out[i] = dis[i]^2 * in[i] + sum_e norm[e] * in[src[e]]
// in is fp16 (halves gather traffic); accumulate fp32; out fp32.
// Segments padded to x8 with (src=0, norm=0); csrc/cnorm pre-zeroed.

__global__ __launch_bounds__(256) void agg128_kernel(
        const __half2* __restrict__ in, float* __restrict__ out,
        const int* __restrict__ offs, const int* __restrict__ counts,
        const int* __restrict__ csrc, const float* __restrict__ cnorm,
        const float* __restrict__ dis, int n) {
    int wid = blockIdx.x * (blockDim.x >> 6) + (threadIdx.x >> 6);
    int lane = threadIdx.x & 63;
    if (wid >= n) return;
    float dd = dis[wid];
    float2 self = __half22float2(in[(size_t)wid * 64 + lane]);
    float a0 = dd * dd * self.x;
    float a1 = dd * dd * self.y;
    int off = offs[wid];
    int pcnt = (counts[wid] + 7) & ~7;
    for (int j = 0; j < pcnt; j += 8) {
        int4 s0 = *(const int4*)&csrc[off + j];
        int4 s1 = *(const int4*)&csrc[off + j + 4];
        float4 n0 = *(const float4*)&cnorm[off + j];
        float4 n1 = *(const float4*)&cnorm[off + j + 4];
        float2 r0 = __half22float2(in[(size_t)s0.x * 64 + lane]);
        float2 r1 = __half22float2(in[(size_t)s0.y * 64 + lane]);
        float2 r2 = __half22float2(in[(size_t)s0.z * 64 + lane]);
        float2 r3 = __half22float2(in[(size_t)s0.w * 64 + lane]);
        float2 r4 = __half22float2(in[(size_t)s1.x * 64 + lane]);
        float2 r5 = __half22float2(in[(size_t)s1.y * 64 + lane]);
        float2 r6 = __half22float2(in[(size_t)s1.z * 64 + lane]);
        float2 r7 = __half22float2(in[(size_t)s1.w * 64 + lane]);
        a0 = fmaf(n0.x, r0.x, a0); a1 = fmaf(n0.x, r0.y, a1);
        a0 = fmaf(n0.y, r1.x, a0); a1 = fmaf(n0.y, r1.y, a1);
        a0 = fmaf(n0.z, r2.x, a0); a1 = fmaf(n0.z, r2.y, a1);
        a0 = fmaf(n0.w, r3.x, a0); a1 = fmaf(n0.w, r3.y, a1);
        a0 = fmaf(n1.x, r4.x, a0); a1 = fmaf(n1.x, r4.y, a1);
        a0 = fmaf(n1.y, r5.x, a0); a1 = fmaf(n1.y, r5.y, a1);
        a0 = fmaf(n1.z, r6.x, a0); a1 = fmaf(n1.z, r6.y, a1);
        a0 = fmaf(n1.w, r7.x, a0); a1 = fmaf(n1.w, r7.y, a1);
    }
    ((float2*)out)[(size_t)wid * 64 + lane] = make_float2(a0, a1);
}

__global__ __launch_bounds__(256) void agg50_kernel(
        const __half* __restrict__ in, float* __restrict__ out,
        const int* __restrict__ offs, const int* __restrict__ counts,
        const int* __restrict__ csrc, const float* __restrict__ cnorm,
        const float* __restrict__ dis, int n) {
    int wid = blockIdx.x * (blockDim.x >> 6) + (threadIdx.x >> 6);
    int lane = threadIdx.x & 63;
    if (wid >= n) return;
    float dd = dis[wid];
    float acc = 0.f;
    if (lane < 50) acc = dd * dd * __half2float(in[(size_t)wid * 50 + lane]);
    int off = offs[wid];
    int pcnt = (counts[wid] + 7) & ~7;
    for (int j = 0; j < pcnt; j += 8) {
        int4 s0 = *(const int4*)&csrc[off + j];
        int4 s1 = *(const int4*)&csrc[off + j + 4];
        float4 n0 = *(const float4*)&cnorm[off + j];
        float4 n1 = *(const float4*)&cnorm[off + j + 4];
        if (lane < 50) {
            float r0 = __half2float(in[(size_t)s0.x * 50 + lane]);
            float r1 = __half2float(in[(size_t)s0.y * 50 + lane]);
            float r2 = __half2float(in[(size_t)s0.z * 50 + lane]);
            float r3 = __half2float(in[(size_t)s0.w * 50 + lane]);
            float r4 = __half2float(in[(size_t)s1.x * 50 + lane]);
            float r5 = __half2float(in[(size_t)s1.y * 50 + lane]);
            float r6 = __half2float(in[(size_t)s1.z * 50 + lane]);
            float r7 = __half2float(in[(size_t)s1.w * 50 + lane]);
            acc = fmaf(n0.x, r0, acc);
            acc = fmaf(n0.y, r1, acc);
            acc = fmaf(n0.z, r2, acc);
            acc = fmaf(n0.w, r3, acc);
            acc = fmaf(n1.x, r4, acc);
            acc = fmaf(n1.y, r5, acc);
            acc = fmaf(n1.z, r6, acc);
            acc = fmaf(n1.w, r7, acc);
        }
    }
    if (lane < 50) out[(size_t)wid * 50 + lane] = acc;
}

// ---------------- tiled SGEMM + bias + activation ----------------
// Block tile: 64 rows x 128 cols, K-step 32. Thread tile: 8 rows x 4 cols.
// A staged TRANSPOSED in LDS. fp32 math; OT selects output type (fp16 for
// layers feeding the next gather, fp32 for the final output).
// ACT: 0 = relu, 1 = sigmoid.
template <int FIN, int FOUT, int ACT, typename OT>
__global__ __launch_bounds__(256) void gemm_act(const float* __restrict__ A,
                                                const float* __restrict__ W,
                                                const float* __restrict__ bias,
                                                OT* __restrict__ out, int n) {
    constexpr int KS = 32;
    constexpr int NKC = (FIN + KS - 1) / KS;
    __shared__ __align__(16) float sAT[KS][68];   // [k][row], stride 68 (16B-aligned rows)
    __shared__ __align__(16) float sW[KS][128];

    const int tid = threadIdx.x;
    const int tx = tid & 31;    // col group: cols tx*4 .. tx*4+3
    const int ty = tid >> 5;    // row group: rows ty*8 .. ty*8+7
    const int rbase = blockIdx.x * 64;

    float acc[8][4];
#pragma unroll
    for (int r = 0; r < 8; ++r)
#pragma unroll
        for (int c = 0; c < 4; ++c) acc[r][c] = 0.f;

    for (int kc = 0; kc < NKC; ++kc) {
        // ---- stage A tile transposed: rows tid>>3 (+32), k-quad (tid&7)*4 ----
        {
            int row = tid >> 3;
            int kq = (tid & 7) * 4;
#pragma unroll
            for (int p = 0; p < 2; ++p, row += 32) {
                int gr = rbase + row;
                float v[4];
                if constexpr (FIN % 4 == 0) {
                    if (gr < n && kc * KS + kq + 3 < FIN) {
                        float4 t4 = *(const float4*)&A[(size_t)gr * FIN + kc * KS + kq];
                        v[0] = t4.x; v[1] = t4.y; v[2] = t4.z; v[3] = t4.w;
                    } else {
#pragma unroll
                        for (int i = 0; i < 4; ++i) {
                            int gk = kc * KS + kq + i;
                            v[i] = (gr < n && gk < FIN) ? A[(size_t)gr * FIN + gk] : 0.f;
                        }
                    }
                } else {
#pragma unroll
                    for (int i = 0; i < 4; ++i) {
                        int gk = kc * KS + kq + i;
                        v[i] = (gr < n && gk < FIN) ? A[(size_t)gr * FIN + gk] : 0.f;
                    }
                }
#pragma unroll
                for (int i = 0; i < 4; ++i) sAT[kq + i][row] = v[i];
            }
        }
        // ---- stage W tile: sW[kr][c], thread: c4=(tid&31)*4, kr=tid>>5 step 8 ----
        {
            int c4 = (tid & 31) * 4;
            int kr = tid >> 5;
#pragma unroll
            for (int p = 0; p < 4; ++p, kr += 8) {
                int gk = kc * KS + kr;
                float v[4];
                if constexpr (FOUT % 4 == 0) {
                    if (gk < FIN) {
                        float4 t4 = *(const float4*)&W[(size_t)gk * FOUT + c4];
                        v[0] = t4.x; v[1] = t4.y; v[2] = t4.z; v[3] = t4.w;
                    } else {
                        v[0] = v[1] = v[2] = v[3] = 0.f;
                    }
                } else {
#pragma unroll
                    for (int i = 0; i < 4; ++i)
                        v[i] = (gk < FIN && c4 + i < FOUT) ? W[(size_t)gk * FOUT + c4 + i] : 0.f;
                }
                *(float4*)&sW[kr][c4] = *(float4*)v;
            }
        }
        __syncthreads();

#pragma unroll
        for (int k = 0; k < KS; ++k) {
            float4 wv = *(const float4*)&sW[k][tx * 4];
            float4 a0 = *(const float4*)&sAT[k][ty * 8];
            float4 a1 = *(const float4*)&sAT[k][ty * 8 + 4];
            const float ar[8] = {a0.x, a0.y, a0.z, a0.w, a1.x, a1.y, a1.z, a1.w};
            const float wc[4] = {wv.x, wv.y, wv.z, wv.w};
#pragma unroll
            for (int r = 0; r < 8; ++r)
#pragma unroll
                for (int c = 0; c < 4; ++c)
                    acc[r][c] = fmaf(ar[r], wc[c], acc[r][c]);
        }
        __syncthreads();
    }

    // ---- epilogue: bias + activation + store ----
    float bv[4];
#pragma unroll
    for (int c = 0; c < 4; ++c)
        bv[c] = (tx * 4 + c < FOUT) ? bias[tx * 4 + c] : 0.f;

#pragma unroll
    for (int r = 0; r < 8; ++r) {
        int gr = rbase + ty * 8 + r;
        if (gr >= n) continue;
        float v[4];
#pragma unroll
        for (int c = 0; c < 4; ++c) {
            float t = acc[r][c] + bv[c];
            if (ACT == 0) t = fmaxf(t, 0.f);
            else t = 1.f / (1.f + __expf(-t));
            v[c] = t;
        }
        if constexpr (sizeof(OT) == 2) {
            __half h4[4];
#pragma unroll
            for (int c = 0; c < 4; ++c) h4[c] = __float2half(v[c]);
            *(uint2*)&out[(size_t)gr * FOUT + tx * 4] = *(uint2*)h4;  // 8B store
        } else if constexpr (FOUT % 4 == 0) {
            *(float4*)&out[(size_t)gr * FOUT + tx * 4] = *(float4*)v;
        } else {
#pragma unroll
            for (int c = 0; c < 4; ++c)
                if (tx * 4 + c < FOUT) out[(size_t)gr * FOUT + tx * 4 + c] = v[c];
        }
    }
}

extern "C" void kernel_launch(void* const* d_in, const int* in_sizes, int n_in,
                              void* d_out, int out_size, void* d_ws, size_t ws_size,
                              hipStream_t stream) {
    const float* x = (const float*)d_in[0];
    const int* eidx = (const int*)d_in[1];
    const float* W1 = (const float*)d_in[2];
    const float* b1 = (const float*)d_in[3];
    const float* W2 = (const float*)d_in[4];
    const float* b2 = (const float*)d_in[5];
    const float* W3 = (const float*)d_in[6];
    const float* b3 = (const float*)d_in[7];
    const float* W4 = (const float*)d_in[8];
    const float* b4 = (const float*)d_in[9];
    float* out = (float*)d_out;

    const int N = NNODES;
    const int E = in_sizes[1] / 2;
    const size_t PE = (size_t)E + 8u * N;  // padded edge-array capacity

    char* ws = (char*)d_ws;
    size_t off = 0;
    auto alloc = [&](size_t bytes) -> char* {
        char* p = ws + off;
        off = (off + bytes + 255) & ~(size_t)255;
        return p;
    };
    float* dis = (float*)alloc((size_t)N * 4);
    int* counts = (int*)alloc((size_t)N * 4);
    int* offs = (int*)alloc((size_t)N * 4);
    int* cursor = (int*)alloc((size_t)N * 4);
    int* bsums = (int*)alloc(128 * 4);
    int* csrc = (int*)alloc(PE * 4);
    float* cnorm = (float*)alloc(PE * 4);
    float* bufA = (float*)alloc((size_t)N * 128 * 4);   // agg output (fp32)
    __half* hH = (__half*)alloc((size_t)N * 128 * 2);   // GEMM output (fp16, gathered)
    __half* x16 = (__half*)alloc((size_t)N * 50 * 2);   // x cast to fp16

    hipMemsetAsync(counts, 0, (size_t)N * 4, stream);
    hipMemsetAsync(cursor, 0, (size_t)N * 4, stream);
    hipMemsetAsync(csrc, 0, PE * 4, stream);   // pad src -> node 0 (valid addr)
    hipMemsetAsync(cnorm, 0, PE * 4, stream);  // pad norm -> 0 contribution

    count_kernel<<<(E + 255) / 256, 256, 0, stream>>>(eidx + E, counts, E);
    dis_kernel<<<(N + 255) / 256, 256, 0, stream>>>(counts, dis, N);
    int nb = (N + 1023) / 1024;
    scan_local<<<nb, 256, 0, stream>>>(counts, offs, bsums, N);
    scan_bsums<<<1, 128, 0, stream>>>(bsums, nb);
    add_base<<<(N + 255) / 256, 256, 0, stream>>>(offs, bsums, N);
    fill_kernel<<<(E + 255) / 256, 256, 0, stream>>>(eidx, offs, cursor, dis, csrc, cnorm, E);
    int nx2 = N * 50 / 2;
    cast_kernel<<<(nx2 + 255) / 256, 256, 0, stream>>>(x, x16, nx2);

    // layer 1: aggregate in 50-dim (fp16 gather), then GEMM 50->128 + relu -> fp16
    agg50_kernel<<<(N + 3) / 4, 256, 0, stream>>>(x16, bufA, offs, counts, csrc, cnorm, dis, N);
    gemm_act<50, 128, 0, __half><<<(N + 63) / 64, 256, 0, stream>>>(bufA, W1, b1, hH, N);
    // layer 2
    agg128_kernel<<<(N + 3) / 4, 256, 0, stream>>>((const __half2*)hH, bufA, offs, counts, csrc, cnorm, dis, N);
    gemm_act<128, 128, 0, __half><<<(N + 63) / 64, 256, 0, stream>>>(bufA, W2, b2, hH, N);
    // layer 3
    agg128_kernel<<<(N + 3) / 4, 256, 0, stream>>>((const __half2*)hH, bufA, offs, counts, csrc, cnorm, dis, N);
    gemm_act<128, 128, 0, __half><<<(N + 63) / 64, 256, 0, stream>>>(bufA, W3, b3, hH, N);
    // layer 4: aggregate 128 (fp16 gather), GEMM 128->121 + sigmoid -> fp32 d_out
    agg128_kernel<<<(N + 3) / 4, 256, 0, stream>>>((const __half2*)hH, bufA, offs, counts, csrc, cnorm, dis, N);
    gemm_act<128, 121, 1, float><<<(N + 63) / 64, 256, 0, stream>>>(bufA, W4, b4, out, N);
}

// Round 5
// 560.210 us; speedup vs baseline: 3.0041x; 1.0923x over previous
//
#include <hip/hip_runtime.h>
#include <math.h>

#define NNODES 100000

typedef _Float16 f16x8 __attribute__((ext_vector_type(8)));
typedef _Float16 f16x2 __attribute__((ext_vector_type(2)));
typedef float f32x4 __attribute__((ext_vector_type(4)));

// ---------------- CSR build (segments padded to multiple of 8) ----------------

__global__ void count_kernel(const int* __restrict__ dst, int* __restrict__ counts, int E) {
    int e = blockIdx.x * 256 + threadIdx.x;
    if (e < E) atomicAdd(&counts[dst[e]], 1);
}

// dis[i] = rsqrt(deg+1) for i<n; dis[n] = 0 (dummy node for pad slots)
__global__ void dis_kernel(const int* __restrict__ counts, float* __restrict__ dis, int n) {
    int i = blockIdx.x * 256 + threadIdx.x;
    if (i < n) dis[i] = rsqrtf((float)(counts[i] + 1));
    else if (i == n) dis[i] = 0.f;
}

// exclusive scan of PADDED counts -> offs; 1024 elements per block (256 thr x 4)
__global__ void scan_local(const int* __restrict__ counts, int* __restrict__ offs,
                           int* __restrict__ bsums, int n) {
    __shared__ int tsum[256];
    int t = threadIdx.x;
    int base = blockIdx.x * 1024 + t * 4;
    int v0 = (base + 0 < n) ? ((counts[base + 0] + 7) & ~7) : 0;
    int v1 = (base + 1 < n) ? ((counts[base + 1] + 7) & ~7) : 0;
    int v2 = (base + 2 < n) ? ((counts[base + 2] + 7) & ~7) : 0;
    int v3 = (base + 3 < n) ? ((counts[base + 3] + 7) & ~7) : 0;
    tsum[t] = v0 + v1 + v2 + v3;
    __syncthreads();
    for (int d = 1; d < 256; d <<= 1) {
        int x = tsum[t];
        int y = (t >= d) ? tsum[t - d] : 0;
        __syncthreads();
        tsum[t] = x + y;
        __syncthreads();
    }
    int prev = (t > 0) ? tsum[t - 1] : 0;
    if (base + 0 < n) offs[base + 0] = prev;
    if (base + 1 < n) offs[base + 1] = prev + v0;
    if (base + 2 < n) offs[base + 2] = prev + v0 + v1;
    if (base + 3 < n) offs[base + 3] = prev + v0 + v1 + v2;
    if (t == 255) bsums[blockIdx.x] = tsum[255];
}

__global__ void scan_bsums(int* __restrict__ bsums, int nb) {
    __shared__ int s[128];
    int t = threadIdx.x;
    s[t] = (t < nb) ? bsums[t] : 0;
    __syncthreads();
    for (int d = 1; d < 128; d <<= 1) {
        int x = s[t];
        int y = (t >= d) ? s[t - d] : 0;
        __syncthreads();
        s[t] = x + y;
        __syncthreads();
    }
    int excl = (t > 0) ? s[t - 1] : 0;
    if (t < nb) bsums[t] = excl;
}

__global__ void add_base(int* __restrict__ offs, const int* __restrict__ bsums, int n) {
    int i = blockIdx.x * 256 + threadIdx.x;
    if (i < n) offs[i] += bsums[i >> 10];
}

// fill only csrc (norm computed in agg from dis table)
__global__ void fill_kernel(const int* __restrict__ eidx, const int* __restrict__ offs,
                            int* __restrict__ cursor, int* __restrict__ csrc, int E) {
    int e = blockIdx.x * 256 + threadIdx.x;
    if (e >= E) return;
    int s = eidx[e];
    int d = eidx[E + e];
    int p = offs[d] + atomicAdd(&cursor[d], 1);
    csrc[p] = s;
}

// fill pad tail of each segment with dummy node N (dis[N]=0 -> zero contribution)
__global__ void pad_kernel(const int* __restrict__ offs, const int* __restrict__ counts,
                           int* __restrict__ csrc, int n) {
    int i = blockIdx.x * 256 + threadIdx.x;
    if (i >= n) return;
    int c = counts[i];
    int p = (c + 7) & ~7;
    int o = offs[i];
    for (int j = c; j < p; ++j) csrc[o + j] = NNODES;
}

// fp32 -> fp16 cast (2 elements per thread)
__global__ void cast_kernel(const float* __restrict__ src, _Float16* __restrict__ dst, int n2) {
    int i = blockIdx.x * 256 + threadIdx.x;
    if (i < n2) {
        float2 v = *(const float2*)&src[i * 2];
        f16x2 h;
        h.x = (_Float16)v.x;
        h.y = (_Float16)v.y;
        *(f16x2*)&dst[i * 2] = h;
    }
}

// ---------------- aggregation: one wave per destination node ----------------
// out[i] = dis[i]^2 * in[i] + sum_e (dis[src]*dis[i]) * in[src[e]]
// in fp16; accumulate fp32; out fp32. Pad slots: src=N, dis[N]=0.

__global__ __launch_bounds__(256) void agg128_kernel(
        const f16x2* __restrict__ in, float* __restrict__ out,
        const int* __restrict__ offs, const int* __restrict__ counts,
        const int* __restrict__ csrc, const float* __restrict__ dis, int n) {
    int wid = blockIdx.x * (blockDim.x >> 6) + (threadIdx.x >> 6);
    int lane = threadIdx.x & 63;
    if (wid >= n) return;
    float dd = dis[wid];
    f16x2 self = in[(size_t)wid * 64 + lane];
    float a0 = dd * dd * (float)self.x;
    float a1 = dd * dd * (float)self.y;
    int off = offs[wid];
    int pcnt = (counts[wid] + 7) & ~7;
    for (int j = 0; j < pcnt; j += 8) {
        int4 s0 = *(const int4*)&csrc[off + j];
        int4 s1 = *(const int4*)&csrc[off + j + 4];
        float v0 = dis[s0.x] * dd, v1 = dis[s0.y] * dd;
        float v2 = dis[s0.z] * dd, v3 = dis[s0.w] * dd;
        float v4 = dis[s1.x] * dd, v5 = dis[s1.y] * dd;
        float v6 = dis[s1.z] * dd, v7 = dis[s1.w] * dd;
        f16x2 r0 = in[(size_t)s0.x * 64 + lane];
        f16x2 r1 = in[(size_t)s0.y * 64 + lane];
        f16x2 r2 = in[(size_t)s0.z * 64 + lane];
        f16x2 r3 = in[(size_t)s0.w * 64 + lane];
        f16x2 r4 = in[(size_t)s1.x * 64 + lane];
        f16x2 r5 = in[(size_t)s1.y * 64 + lane];
        f16x2 r6 = in[(size_t)s1.z * 64 + lane];
        f16x2 r7 = in[(size_t)s1.w * 64 + lane];
        a0 = fmaf(v0, (float)r0.x, a0); a1 = fmaf(v0, (float)r0.y, a1);
        a0 = fmaf(v1, (float)r1.x, a0); a1 = fmaf(v1, (float)r1.y, a1);
        a0 = fmaf(v2, (float)r2.x, a0); a1 = fmaf(v2, (float)r2.y, a1);
        a0 = fmaf(v3, (float)r3.x, a0); a1 = fmaf(v3, (float)r3.y, a1);
        a0 = fmaf(v4, (float)r4.x, a0); a1 = fmaf(v4, (float)r4.y, a1);
        a0 = fmaf(v5, (float)r5.x, a0); a1 = fmaf(v5, (float)r5.y, a1);
        a0 = fmaf(v6, (float)r6.x, a0); a1 = fmaf(v6, (float)r6.y, a1);
        a0 = fmaf(v7, (float)r7.x, a0); a1 = fmaf(v7, (float)r7.y, a1);
    }
    ((float2*)out)[(size_t)wid * 64 + lane] = make_float2(a0, a1);
}

// 50-dim variant: output stride 64 with zero pad (feeds K=64 MFMA GEMM)
__global__ __launch_bounds__(256) void agg50_kernel(
        const _Float16* __restrict__ in, float* __restrict__ out,
        const int* __restrict__ offs, const int* __restrict__ counts,
        const int* __restrict__ csrc, const float* __restrict__ dis, int n) {
    int wid = blockIdx.x * (blockDim.x >> 6) + (threadIdx.x >> 6);
    int lane = threadIdx.x & 63;
    if (wid >= n) return;
    float dd = dis[wid];
    float acc = 0.f;
    if (lane < 50) acc = dd * dd * (float)in[(size_t)wid * 50 + lane];
    int off = offs[wid];
    int pcnt = (counts[wid] + 7) & ~7;
    for (int j = 0; j < pcnt; j += 8) {
        int4 s0 = *(const int4*)&csrc[off + j];
        int4 s1 = *(const int4*)&csrc[off + j + 4];
        float v0 = dis[s0.x] * dd, v1 = dis[s0.y] * dd;
        float v2 = dis[s0.z] * dd, v3 = dis[s0.w] * dd;
        float v4 = dis[s1.x] * dd, v5 = dis[s1.y] * dd;
        float v6 = dis[s1.z] * dd, v7 = dis[s1.w] * dd;
        if (lane < 50) {
            float r0 = (float)in[(size_t)s0.x * 50 + lane];
            float r1 = (float)in[(size_t)s0.y * 50 + lane];
            float r2 = (float)in[(size_t)s0.z * 50 + lane];
            float r3 = (float)in[(size_t)s0.w * 50 + lane];
            float r4 = (float)in[(size_t)s1.x * 50 + lane];
            float r5 = (float)in[(size_t)s1.y * 50 + lane];
            float r6 = (float)in[(size_t)s1.z * 50 + lane];
            float r7 = (float)in[(size_t)s1.w * 50 + lane];
            acc = fmaf(v0, r0, acc);
            acc = fmaf(v1, r1, acc);
            acc = fmaf(v2, r2, acc);
            acc = fmaf(v3, r3, acc);
            acc = fmaf(v4, r4, acc);
            acc = fmaf(v5, r5, acc);
            acc = fmaf(v6, r6, acc);
            acc = fmaf(v7, r7, acc);
        }
    }
    out[(size_t)wid * 64 + lane] = (lane < 50) ? acc : 0.f;
}

// ---------------- W -> per-lane fragment order (fp16), once per launch ------
// frag[(kc*CTN+ct)*64 + lane][j] = fp16(W[kc*32 + (lane>>4)*8 + j][ct*16 + (lane&15)])
__global__ void wfrag_kernel(const float* __restrict__ W, f16x8* __restrict__ frag,
                             int FIN, int FOUT, int KCN, int CTN) {
    int idx = blockIdx.x * 256 + threadIdx.x;
    int tot = KCN * CTN * 64;
    if (idx >= tot) return;
    int lane = idx & 63;
    int ct = (idx >> 6) % CTN;
    int kc = (idx >> 6) / CTN;
    int c = ct * 16 + (lane & 15);
    int kb = kc * 32 + (lane >> 4) * 8;
    f16x8 v;
#pragma unroll
    for (int j = 0; j < 8; ++j) {
        int k = kb + j;
        float w = (k < FIN && c < FOUT) ? W[(size_t)k * FOUT + c] : 0.f;
        v[j] = (_Float16)w;
    }
    frag[idx] = v;
}

// ---------------- MFMA GEMM + bias + activation ----------------
// 1 wave = 16 rows x (CTN*16) cols. A fp32 split hi+lo fp16 (2 MFMAs/frag) so
// only W carries fp16 rounding. No LDS, no barriers. ACT: 0=relu, 1=sigmoid.
// MFMA 16x16x32 f16: A/B lane frag: r/c=lane&15, k=(lane>>4)*8+j. D: col=lane&15,
// row=(lane>>4)*4+reg.
template <int KCN, int CTN, int ACT, typename OT>
__global__ __launch_bounds__(256) void gemm_mfma(
        const float* __restrict__ A, int lda,
        const f16x8* __restrict__ wfrag,
        const float* __restrict__ bias, int fout,
        OT* __restrict__ out, int ldo, int n) {
    int wid = blockIdx.x * 4 + (threadIdx.x >> 6);
    int lane = threadIdx.x & 63;
    int rbase = wid * 16;
    if (rbase >= n) return;
    int r = lane & 15;
    int g = lane >> 4;
    int gr = rbase + r;
    const float* arow = A + (size_t)((gr < n) ? gr : 0) * lda + g * 8;

    f32x4 acc[CTN];
#pragma unroll
    for (int ct = 0; ct < CTN; ++ct) acc[ct] = (f32x4){0.f, 0.f, 0.f, 0.f};

#pragma unroll
    for (int kc = 0; kc < KCN; ++kc) {
        float4 a0 = *(const float4*)(arow + kc * 32);
        float4 a1 = *(const float4*)(arow + kc * 32 + 4);
        float av[8] = {a0.x, a0.y, a0.z, a0.w, a1.x, a1.y, a1.z, a1.w};
        f16x8 ahi, alo;
#pragma unroll
        for (int j = 0; j < 8; ++j) {
            _Float16 h = (_Float16)av[j];
            ahi[j] = h;
            alo[j] = (_Float16)(av[j] - (float)h);
        }
        const f16x8* wk = wfrag + (size_t)(kc * CTN) * 64 + lane;
#pragma unroll
        for (int ct = 0; ct < CTN; ++ct) {
            f16x8 b = wk[(size_t)ct * 64];
            acc[ct] = __builtin_amdgcn_mfma_f32_16x16x32_f16(ahi, b, acc[ct], 0, 0, 0);
            acc[ct] = __builtin_amdgcn_mfma_f32_16x16x32_f16(alo, b, acc[ct], 0, 0, 0);
        }
    }

    int orow0 = rbase + g * 4;
#pragma unroll
    for (int ct = 0; ct < CTN; ++ct) {
        int col = ct * 16 + (lane & 15);
        if (col >= fout) continue;
        float bv = bias[col];
#pragma unroll
        for (int q = 0; q < 4; ++q) {
            int orow = orow0 + q;
            if (orow >= n) continue;
            float v = acc[ct][q] + bv;
            if (ACT == 0) v = fmaxf(v, 0.f);
            else v = 1.f / (1.f + __expf(-v));
            out[(size_t)orow * ldo + col] = (OT)v;
        }
    }
}

extern "C" void kernel_launch(void* const* d_in, const int* in_sizes, int n_in,
                              void* d_out, int out_size, void* d_ws, size_t ws_size,
                              hipStream_t stream) {
    const float* x = (const float*)d_in[0];
    const int* eidx = (const int*)d_in[1];
    const float* W1 = (const float*)d_in[2];
    const float* b1 = (const float*)d_in[3];
    const float* W2 = (const float*)d_in[4];
    const float* b2 = (const float*)d_in[5];
    const float* W3 = (const float*)d_in[6];
    const float* b3 = (const float*)d_in[7];
    const float* W4 = (const float*)d_in[8];
    const float* b4 = (const float*)d_in[9];
    float* out = (float*)d_out;

    const int N = NNODES;
    const int E = in_sizes[1] / 2;
    const size_t PE = (size_t)E + 8u * N;  // padded edge-array capacity

    char* ws = (char*)d_ws;
    size_t off = 0;
    auto alloc = [&](size_t bytes) -> char* {
        char* p = ws + off;
        off = (off + bytes + 255) & ~(size_t)255;
        return p;
    };
    float* dis = (float*)alloc((size_t)(N + 1) * 4);
    int* counts = (int*)alloc((size_t)N * 4);
    int* offs = (int*)alloc((size_t)N * 4);
    int* cursor = (int*)alloc((size_t)N * 4);
    int* bsums = (int*)alloc(128 * 4);
    int* csrc = (int*)alloc(PE * 4);
    float* bufA = (float*)alloc((size_t)N * 128 * 4);        // agg output (fp32)
    _Float16* hH = (_Float16*)alloc((size_t)(N + 1) * 128 * 2);  // h fp16 (gathered)
    _Float16* x16 = (_Float16*)alloc((size_t)(N + 1) * 50 * 2);  // x fp16
    f16x8* wf1 = (f16x8*)alloc((size_t)2 * 8 * 64 * 16);
    f16x8* wf2 = (f16x8*)alloc((size_t)4 * 8 * 64 * 16);
    f16x8* wf3 = (f16x8*)alloc((size_t)4 * 8 * 64 * 16);
    f16x8* wf4 = (f16x8*)alloc((size_t)4 * 8 * 64 * 16);

    hipMemsetAsync(counts, 0, (size_t)N * 4, stream);
    hipMemsetAsync(cursor, 0, (size_t)N * 4, stream);

    // weight fragments (once per launch)
    wfrag_kernel<<<(2 * 8 * 64 + 255) / 256, 256, 0, stream>>>(W1, wf1, 50, 128, 2, 8);
    wfrag_kernel<<<(4 * 8 * 64 + 255) / 256, 256, 0, stream>>>(W2, wf2, 128, 128, 4, 8);
    wfrag_kernel<<<(4 * 8 * 64 + 255) / 256, 256, 0, stream>>>(W3, wf3, 128, 128, 4, 8);
    wfrag_kernel<<<(4 * 8 * 64 + 255) / 256, 256, 0, stream>>>(W4, wf4, 128, 121, 4, 8);

    // CSR build
    count_kernel<<<(E + 255) / 256, 256, 0, stream>>>(eidx + E, counts, E);
    dis_kernel<<<(N + 256) / 256, 256, 0, stream>>>(counts, dis, N);
    int nb = (N + 1023) / 1024;
    scan_local<<<nb, 256, 0, stream>>>(counts, offs, bsums, N);
    scan_bsums<<<1, 128, 0, stream>>>(bsums, nb);
    add_base<<<(N + 255) / 256, 256, 0, stream>>>(offs, bsums, N);
    fill_kernel<<<(E + 255) / 256, 256, 0, stream>>>(eidx, offs, cursor, csrc, E);
    pad_kernel<<<(N + 255) / 256, 256, 0, stream>>>(offs, counts, csrc, N);

    int nx2 = N * 50 / 2;
    cast_kernel<<<(nx2 + 255) / 256, 256, 0, stream>>>(x, x16, nx2);

    int gblocks = ((N + 15) / 16 + 3) / 4;
    // layer 1: agg 50-dim (fp16 gather) -> bufA[.][64] ; MFMA GEMM 64->128 + relu -> fp16
    agg50_kernel<<<(N + 3) / 4, 256, 0, stream>>>(x16, bufA, offs, counts, csrc, dis, N);
    gemm_mfma<2, 8, 0, _Float16><<<gblocks, 256, 0, stream>>>(bufA, 64, wf1, b1, 128, hH, 128, N);
    // layer 2
    agg128_kernel<<<(N + 3) / 4, 256, 0, stream>>>((const f16x2*)hH, bufA, offs, counts, csrc, dis, N);
    gemm_mfma<4, 8, 0, _Float16><<<gblocks, 256, 0, stream>>>(bufA, 128, wf2, b2, 128, hH, 128, N);
    // layer 3
    agg128_kernel<<<(N + 3) / 4, 256, 0, stream>>>((const f16x2*)hH, bufA, offs, counts, csrc, dis, N);
    gemm_mfma<4, 8, 0, _Float16><<<gblocks, 256, 0, stream>>>(bufA, 128, wf3, b3, 128, hH, 128, N);
    // layer 4: agg 128 -> MFMA GEMM 128->121 + sigmoid -> fp32 d_out
    agg128_kernel<<<(N + 3) / 4, 256, 0, stream>>>((const f16x2*)hH, bufA, offs, counts, csrc, dis, N);
    gemm_mfma<4, 8, 1, float><<<gblocks, 256, 0, stream>>>(bufA, 128, wf4, b4, 121, out, 121, N);
}

// Round 6
// 537.722 us; speedup vs baseline: 3.1297x; 1.0418x over previous
//
#include <hip/hip_runtime.h>
#include <math.h>

#define NNODES 100000
#define BSHIFT 9
#define NBKT ((NNODES + (1 << BSHIFT) - 1) >> BSHIFT)   // 196 buckets of 512 nodes
#define CAPB 10240                                       // >= 8192 expected + 22 sigma
#define CHUNK 2048

typedef _Float16 f16x8 __attribute__((ext_vector_type(8)));
typedef _Float16 f16x2 __attribute__((ext_vector_type(2)));
typedef float f32x4 __attribute__((ext_vector_type(4)));

// ---------------- phase 1: bin edges by dst bucket + per-node counts --------
__global__ __launch_bounds__(256) void bin_kernel(
        const int* __restrict__ eidx, int E,
        int* __restrict__ counts, uint2* __restrict__ bedge, int* __restrict__ bcur) {
    __shared__ int hist[256];
    __shared__ int scanx[256];
    __shared__ int gbase[256];
    __shared__ uint2 stage[CHUNK];
    int tid = threadIdx.x;
    int nchunk = (E + CHUNK - 1) / CHUNK;
    for (int c = blockIdx.x; c < nchunk; c += gridDim.x) {
        int base = c * CHUNK;
        int m = min(CHUNK, E - base);
        hist[tid] = 0;
        __syncthreads();
        int s[8], d[8], b[8], r[8];
#pragma unroll
        for (int j = 0; j < 8; ++j) {
            int rel = j * 256 + tid;
            bool ok = rel < m;
            int e = base + (ok ? rel : 0);
            s[j] = eidx[e];
            d[j] = eidx[E + e];
            b[j] = d[j] >> BSHIFT;
            if (ok) {
                r[j] = atomicAdd(&hist[b[j]], 1);
                atomicAdd(&counts[d[j]], 1);
            } else {
                r[j] = -1;
            }
        }
        __syncthreads();
        // block-wide inclusive scan of hist -> scanx, then make exclusive
        int h = hist[tid];
        scanx[tid] = h;
        __syncthreads();
        for (int st = 1; st < 256; st <<= 1) {
            int y = (tid >= st) ? scanx[tid - st] : 0;
            __syncthreads();
            scanx[tid] += y;
            __syncthreads();
        }
        int excl = scanx[tid] - h;
        if (h > 0) gbase[tid] = atomicAdd(&bcur[tid], h);
        __syncthreads();
        scanx[tid] = excl;
        __syncthreads();
        // stage bin-grouped
#pragma unroll
        for (int j = 0; j < 8; ++j) {
            if (r[j] >= 0)
                stage[scanx[b[j]] + r[j]] = make_uint2((unsigned)s[j], (unsigned)d[j]);
        }
        __syncthreads();
        // flush: contiguous per-bin chunks to global
        for (int i = tid; i < m; i += 256) {
            int lo = 0, hi = 255;
            while (lo < hi) {
                int mid = (lo + hi + 1) >> 1;
                if (scanx[mid] <= i) lo = mid; else hi = mid - 1;
            }
            int idx = gbase[lo] + (i - scanx[lo]);
            if (idx < CAPB) bedge[(size_t)lo * CAPB + idx] = stage[i];
        }
        __syncthreads();
    }
}

// ---------------- phase 2: bucket-local CSR fill (one block per bucket) -----
__global__ __launch_bounds__(512) void fill2_kernel(
        const uint2* __restrict__ bedge, const int* __restrict__ bcur,
        const int* __restrict__ offs, int* __restrict__ cursor,
        int* __restrict__ csrc) {
    int b = blockIdx.x;
    int cnt = min(bcur[b], CAPB);
    const uint2* e = bedge + (size_t)b * CAPB;
    for (int i = threadIdx.x; i < cnt; i += 512) {
        uint2 ed = e[i];
        int p = offs[ed.y] + atomicAdd(&cursor[ed.y], 1);
        csrc[p] = (int)ed.x;
    }
}

// dis[i] = rsqrt(deg+1) for i<n; dis[n] = 0 (dummy node for pad slots)
__global__ void dis_kernel(const int* __restrict__ counts, float* __restrict__ dis, int n) {
    int i = blockIdx.x * 256 + threadIdx.x;
    if (i < n) dis[i] = rsqrtf((float)(counts[i] + 1));
    else if (i == n) dis[i] = 0.f;
}

// exclusive scan of PADDED counts -> offs; 1024 elements per block (256 thr x 4)
__global__ void scan_local(const int* __restrict__ counts, int* __restrict__ offs,
                           int* __restrict__ bsums, int n) {
    __shared__ int tsum[256];
    int t = threadIdx.x;
    int base = blockIdx.x * 1024 + t * 4;
    int v0 = (base + 0 < n) ? ((counts[base + 0] + 7) & ~7) : 0;
    int v1 = (base + 1 < n) ? ((counts[base + 1] + 7) & ~7) : 0;
    int v2 = (base + 2 < n) ? ((counts[base + 2] + 7) & ~7) : 0;
    int v3 = (base + 3 < n) ? ((counts[base + 3] + 7) & ~7) : 0;
    tsum[t] = v0 + v1 + v2 + v3;
    __syncthreads();
    for (int d = 1; d < 256; d <<= 1) {
        int x = tsum[t];
        int y = (t >= d) ? tsum[t - d] : 0;
        __syncthreads();
        tsum[t] = x + y;
        __syncthreads();
    }
    int prev = (t > 0) ? tsum[t - 1] : 0;
    if (base + 0 < n) offs[base + 0] = prev;
    if (base + 1 < n) offs[base + 1] = prev + v0;
    if (base + 2 < n) offs[base + 2] = prev + v0 + v1;
    if (base + 3 < n) offs[base + 3] = prev + v0 + v1 + v2;
    if (t == 255) bsums[blockIdx.x] = tsum[255];
}

__global__ void scan_bsums(int* __restrict__ bsums, int nb) {
    __shared__ int s[128];
    int t = threadIdx.x;
    s[t] = (t < nb) ? bsums[t] : 0;
    __syncthreads();
    for (int d = 1; d < 128; d <<= 1) {
        int x = s[t];
        int y = (t >= d) ? s[t - d] : 0;
        __syncthreads();
        s[t] = x + y;
        __syncthreads();
    }
    int excl = (t > 0) ? s[t - 1] : 0;
    if (t < nb) bsums[t] = excl;
}

__global__ void add_base(int* __restrict__ offs, const int* __restrict__ bsums, int n) {
    int i = blockIdx.x * 256 + threadIdx.x;
    if (i < n) offs[i] += bsums[i >> 10];
}

// fill pad tail of each segment with dummy node N (dis[N]=0 -> zero contribution)
__global__ void pad_kernel(const int* __restrict__ offs, const int* __restrict__ counts,
                           int* __restrict__ csrc, int n) {
    int i = blockIdx.x * 256 + threadIdx.x;
    if (i >= n) return;
    int c = counts[i];
    int p = (c + 7) & ~7;
    int o = offs[i];
    for (int j = c; j < p; ++j) csrc[o + j] = NNODES;
}

// fp32 -> fp16 cast (2 elements per thread)
__global__ void cast_kernel(const float* __restrict__ src, _Float16* __restrict__ dst, int n2) {
    int i = blockIdx.x * 256 + threadIdx.x;
    if (i < n2) {
        float2 v = *(const float2*)&src[i * 2];
        f16x2 h;
        h.x = (_Float16)v.x;
        h.y = (_Float16)v.y;
        *(f16x2*)&dst[i * 2] = h;
    }
}

// ---------------- aggregation: one wave per destination node ----------------
// out[i] = dis[i]^2 * in[i] + sum_e (dis[src]*dis[i]) * in[src[e]]
// in fp16; accumulate fp32; out fp32. Pad slots: src=N, dis[N]=0.

__global__ __launch_bounds__(256) void agg128_kernel(
        const f16x2* __restrict__ in, float* __restrict__ out,
        const int* __restrict__ offs, const int* __restrict__ counts,
        const int* __restrict__ csrc, const float* __restrict__ dis, int n) {
    int wid = blockIdx.x * (blockDim.x >> 6) + (threadIdx.x >> 6);
    int lane = threadIdx.x & 63;
    if (wid >= n) return;
    float dd = dis[wid];
    f16x2 self = in[(size_t)wid * 64 + lane];
    float a0 = dd * dd * (float)self.x;
    float a1 = dd * dd * (float)self.y;
    int off = offs[wid];
    int pcnt = (counts[wid] + 7) & ~7;
    for (int j = 0; j < pcnt; j += 8) {
        int4 s0 = *(const int4*)&csrc[off + j];
        int4 s1 = *(const int4*)&csrc[off + j + 4];
        float v0 = dis[s0.x] * dd, v1 = dis[s0.y] * dd;
        float v2 = dis[s0.z] * dd, v3 = dis[s0.w] * dd;
        float v4 = dis[s1.x] * dd, v5 = dis[s1.y] * dd;
        float v6 = dis[s1.z] * dd, v7 = dis[s1.w] * dd;
        f16x2 r0 = in[(size_t)s0.x * 64 + lane];
        f16x2 r1 = in[(size_t)s0.y * 64 + lane];
        f16x2 r2 = in[(size_t)s0.z * 64 + lane];
        f16x2 r3 = in[(size_t)s0.w * 64 + lane];
        f16x2 r4 = in[(size_t)s1.x * 64 + lane];
        f16x2 r5 = in[(size_t)s1.y * 64 + lane];
        f16x2 r6 = in[(size_t)s1.z * 64 + lane];
        f16x2 r7 = in[(size_t)s1.w * 64 + lane];
        a0 = fmaf(v0, (float)r0.x, a0); a1 = fmaf(v0, (float)r0.y, a1);
        a0 = fmaf(v1, (float)r1.x, a0); a1 = fmaf(v1, (float)r1.y, a1);
        a0 = fmaf(v2, (float)r2.x, a0); a1 = fmaf(v2, (float)r2.y, a1);
        a0 = fmaf(v3, (float)r3.x, a0); a1 = fmaf(v3, (float)r3.y, a1);
        a0 = fmaf(v4, (float)r4.x, a0); a1 = fmaf(v4, (float)r4.y, a1);
        a0 = fmaf(v5, (float)r5.x, a0); a1 = fmaf(v5, (float)r5.y, a1);
        a0 = fmaf(v6, (float)r6.x, a0); a1 = fmaf(v6, (float)r6.y, a1);
        a0 = fmaf(v7, (float)r7.x, a0); a1 = fmaf(v7, (float)r7.y, a1);
    }
    ((float2*)out)[(size_t)wid * 64 + lane] = make_float2(a0, a1);
}

// 50-dim variant: output stride 64 with zero pad (feeds K=64 MFMA GEMM)
__global__ __launch_bounds__(256) void agg50_kernel(
        const _Float16* __restrict__ in, float* __restrict__ out,
        const int* __restrict__ offs, const int* __restrict__ counts,
        const int* __restrict__ csrc, const float* __restrict__ dis, int n) {
    int wid = blockIdx.x * (blockDim.x >> 6) + (threadIdx.x >> 6);
    int lane = threadIdx.x & 63;
    if (wid >= n) return;
    float dd = dis[wid];
    float acc = 0.f;
    if (lane < 50) acc = dd * dd * (float)in[(size_t)wid * 50 + lane];
    int off = offs[wid];
    int pcnt = (counts[wid] + 7) & ~7;
    for (int j = 0; j < pcnt; j += 8) {
        int4 s0 = *(const int4*)&csrc[off + j];
        int4 s1 = *(const int4*)&csrc[off + j + 4];
        float v0 = dis[s0.x] * dd, v1 = dis[s0.y] * dd;
        float v2 = dis[s0.z] * dd, v3 = dis[s0.w] * dd;
        float v4 = dis[s1.x] * dd, v5 = dis[s1.y] * dd;
        float v6 = dis[s1.z] * dd, v7 = dis[s1.w] * dd;
        if (lane < 50) {
            float r0 = (float)in[(size_t)s0.x * 50 + lane];
            float r1 = (float)in[(size_t)s0.y * 50 + lane];
            float r2 = (float)in[(size_t)s0.z * 50 + lane];
            float r3 = (float)in[(size_t)s0.w * 50 + lane];
            float r4 = (float)in[(size_t)s1.x * 50 + lane];
            float r5 = (float)in[(size_t)s1.y * 50 + lane];
            float r6 = (float)in[(size_t)s1.z * 50 + lane];
            float r7 = (float)in[(size_t)s1.w * 50 + lane];
            acc = fmaf(v0, r0, acc);
            acc = fmaf(v1, r1, acc);
            acc = fmaf(v2, r2, acc);
            acc = fmaf(v3, r3, acc);
            acc = fmaf(v4, r4, acc);
            acc = fmaf(v5, r5, acc);
            acc = fmaf(v6, r6, acc);
            acc = fmaf(v7, r7, acc);
        }
    }
    out[(size_t)wid * 64 + lane] = (lane < 50) ? acc : 0.f;
}

// ---------------- W -> per-lane fragment order (fp16), once per launch ------
__global__ void wfrag_kernel(const float* __restrict__ W, f16x8* __restrict__ frag,
                             int FIN, int FOUT, int KCN, int CTN) {
    int idx = blockIdx.x * 256 + threadIdx.x;
    int tot = KCN * CTN * 64;
    if (idx >= tot) return;
    int lane = idx & 63;
    int ct = (idx >> 6) % CTN;
    int kc = (idx >> 6) / CTN;
    int c = ct * 16 + (lane & 15);
    int kb = kc * 32 + (lane >> 4) * 8;
    f16x8 v;
#pragma unroll
    for (int j = 0; j < 8; ++j) {
        int k = kb + j;
        float w = (k < FIN && c < FOUT) ? W[(size_t)k * FOUT + c] : 0.f;
        v[j] = (_Float16)w;
    }
    frag[idx] = v;
}

// ---------------- MFMA GEMM + bias + activation ----------------
// 1 wave = 16 rows x (CTN*16) cols. A fp32 split hi+lo fp16 (2 MFMAs/frag) so
// only W carries fp16 rounding. No LDS, no barriers. ACT: 0=relu, 1=sigmoid.
template <int KCN, int CTN, int ACT, typename OT>
__global__ __launch_bounds__(256) void gemm_mfma(
        const float* __restrict__ A, int lda,
        const f16x8* __restrict__ wfrag,
        const float* __restrict__ bias, int fout,
        OT* __restrict__ out, int ldo, int n) {
    int wid = blockIdx.x * 4 + (threadIdx.x >> 6);
    int lane = threadIdx.x & 63;
    int rbase = wid * 16;
    if (rbase >= n) return;
    int r = lane & 15;
    int g = lane >> 4;
    int gr = rbase + r;
    const float* arow = A + (size_t)((gr < n) ? gr : 0) * lda + g * 8;

    f32x4 acc[CTN];
#pragma unroll
    for (int ct = 0; ct < CTN; ++ct) acc[ct] = (f32x4){0.f, 0.f, 0.f, 0.f};

#pragma unroll
    for (int kc = 0; kc < KCN; ++kc) {
        float4 a0 = *(const float4*)(arow + kc * 32);
        float4 a1 = *(const float4*)(arow + kc * 32 + 4);
        float av[8] = {a0.x, a0.y, a0.z, a0.w, a1.x, a1.y, a1.z, a1.w};
        f16x8 ahi, alo;
#pragma unroll
        for (int j = 0; j < 8; ++j) {
            _Float16 h = (_Float16)av[j];
            ahi[j] = h;
            alo[j] = (_Float16)(av[j] - (float)h);
        }
        const f16x8* wk = wfrag + (size_t)(kc * CTN) * 64 + lane;
#pragma unroll
        for (int ct = 0; ct < CTN; ++ct) {
            f16x8 b = wk[(size_t)ct * 64];
            acc[ct] = __builtin_amdgcn_mfma_f32_16x16x32_f16(ahi, b, acc[ct], 0, 0, 0);
            acc[ct] = __builtin_amdgcn_mfma_f32_16x16x32_f16(alo, b, acc[ct], 0, 0, 0);
        }
    }

    int orow0 = rbase + g * 4;
#pragma unroll
    for (int ct = 0; ct < CTN; ++ct) {
        int col = ct * 16 + (lane & 15);
        if (col >= fout) continue;
        float bv = bias[col];
#pragma unroll
        for (int q = 0; q < 4; ++q) {
            int orow = orow0 + q;
            if (orow >= n) continue;
            float v = acc[ct][q] + bv;
            if (ACT == 0) v = fmaxf(v, 0.f);
            else v = 1.f / (1.f + __expf(-v));
            out[(size_t)orow * ldo + col] = (OT)v;
        }
    }
}

extern "C" void kernel_launch(void* const* d_in, const int* in_sizes, int n_in,
                              void* d_out, int out_size, void* d_ws, size_t ws_size,
                              hipStream_t stream) {
    const float* x = (const float*)d_in[0];
    const int* eidx = (const int*)d_in[1];
    const float* W1 = (const float*)d_in[2];
    const float* b1 = (const float*)d_in[3];
    const float* W2 = (const float*)d_in[4];
    const float* b2 = (const float*)d_in[5];
    const float* W3 = (const float*)d_in[6];
    const float* b3 = (const float*)d_in[7];
    const float* W4 = (const float*)d_in[8];
    const float* b4 = (const float*)d_in[9];
    float* out = (float*)d_out;

    const int N = NNODES;
    const int E = in_sizes[1] / 2;
    const size_t PE = (size_t)E + 8u * N;  // padded edge-array capacity

    char* ws = (char*)d_ws;
    size_t off = 0;
    auto alloc = [&](size_t bytes) -> char* {
        char* p = ws + off;
        off = (off + bytes + 255) & ~(size_t)255;
        return p;
    };
    float* dis = (float*)alloc((size_t)(N + 1) * 4);
    int* counts = (int*)alloc((size_t)N * 4);
    int* offs = (int*)alloc((size_t)N * 4);
    int* cursor = (int*)alloc((size_t)N * 4);
    int* bsums = (int*)alloc(128 * 4);
    int* bcur = (int*)alloc(256 * 4);
    int* csrc = (int*)alloc(PE * 4);
    float* bufA = (float*)alloc((size_t)N * 128 * 4);        // agg output (fp32)
    _Float16* hH = (_Float16*)alloc((size_t)(N + 1) * 128 * 2);  // h fp16 (gathered)
    _Float16* x16 = (_Float16*)alloc((size_t)(N + 1) * 50 * 2);  // x fp16
    f16x8* wf1 = (f16x8*)alloc((size_t)2 * 8 * 64 * 16);
    f16x8* wf2 = (f16x8*)alloc((size_t)4 * 8 * 64 * 16);
    f16x8* wf3 = (f16x8*)alloc((size_t)4 * 8 * 64 * 16);
    f16x8* wf4 = (f16x8*)alloc((size_t)4 * 8 * 64 * 16);
    // bedge aliases bufA: only live before any agg/gemm writes bufA
    uint2* bedge = (uint2*)bufA;   // NBKT*CAPB*8 = ~16MB < 51MB

    hipMemsetAsync(counts, 0, (size_t)N * 4, stream);
    hipMemsetAsync(cursor, 0, (size_t)N * 4, stream);
    hipMemsetAsync(bcur, 0, 256 * 4, stream);

    // weight fragments (once per launch)
    wfrag_kernel<<<(2 * 8 * 64 + 255) / 256, 256, 0, stream>>>(W1, wf1, 50, 128, 2, 8);
    wfrag_kernel<<<(4 * 8 * 64 + 255) / 256, 256, 0, stream>>>(W2, wf2, 128, 128, 4, 8);
    wfrag_kernel<<<(4 * 8 * 64 + 255) / 256, 256, 0, stream>>>(W3, wf3, 128, 128, 4, 8);
    wfrag_kernel<<<(4 * 8 * 64 + 255) / 256, 256, 0, stream>>>(W4, wf4, 128, 121, 4, 8);

    // CSR build: bin (+counts) -> dis -> scan -> bucket-local fill -> pad
    bin_kernel<<<256, 256, 0, stream>>>(eidx, E, counts, bedge, bcur);
    dis_kernel<<<(N + 256) / 256, 256, 0, stream>>>(counts, dis, N);
    int nb = (N + 1023) / 1024;
    scan_local<<<nb, 256, 0, stream>>>(counts, offs, bsums, N);
    scan_bsums<<<1, 128, 0, stream>>>(bsums, nb);
    add_base<<<(N + 255) / 256, 256, 0, stream>>>(offs, bsums, N);
    fill2_kernel<<<NBKT, 512, 0, stream>>>(bedge, bcur, offs, cursor, csrc);
    pad_kernel<<<(N + 255) / 256, 256, 0, stream>>>(offs, counts, csrc, N);

    int nx2 = N * 50 / 2;
    cast_kernel<<<(nx2 + 255) / 256, 256, 0, stream>>>(x, x16, nx2);

    int gblocks = ((N + 15) / 16 + 3) / 4;
    // layer 1: agg 50-dim (fp16 gather) -> bufA[.][64] ; MFMA GEMM 64->128 + relu -> fp16
    agg50_kernel<<<(N + 3) / 4, 256, 0, stream>>>(x16, bufA, offs, counts, csrc, dis, N);
    gemm_mfma<2, 8, 0, _Float16><<<gblocks, 256, 0, stream>>>(bufA, 64, wf1, b1, 128, hH, 128, N);
    // layer 2
    agg128_kernel<<<(N + 3) / 4, 256, 0, stream>>>((const f16x2*)hH, bufA, offs, counts, csrc, dis, N);
    gemm_mfma<4, 8, 0, _Float16><<<gblocks, 256, 0, stream>>>(bufA, 128, wf2, b2, 128, hH, 128, N);
    // layer 3
    agg128_kernel<<<(N + 3) / 4, 256, 0, stream>>>((const f16x2*)hH, bufA, offs, counts, csrc, dis, N);
    gemm_mfma<4, 8, 0, _Float16><<<gblocks, 256, 0, stream>>>(bufA, 128, wf3, b3, 128, hH, 128, N);
    // layer 4: agg 128 -> MFMA GEMM 128->121 + sigmoid -> fp32 d_out
    agg128_kernel<<<(N + 3) / 4, 256, 0, stream>>>((const f16x2*)hH, bufA, offs, counts, csrc, dis, N);
    gemm_mfma<4, 8, 1, float><<<gblocks, 256, 0, stream>>>(bufA, 128, wf4, b4, 121, out, 121, N);
}

// Round 7
// 429.086 us; speedup vs baseline: 3.9221x; 1.2532x over previous
//
#include <hip/hip_runtime.h>
#include <math.h>

#define NNODES 100000
#define BSHIFT 9
#define NBKT ((NNODES + (1 << BSHIFT) - 1) >> BSHIFT)   // 196 buckets of 512 nodes
#define CAPB 10240                                       // expected 8163 + 23 sigma
#define CHUNK 2048

typedef _Float16 f16x8 __attribute__((ext_vector_type(8)));
typedef _Float16 f16x2 __attribute__((ext_vector_type(2)));
typedef float f32x4 __attribute__((ext_vector_type(4)));

// ---------------- phase 1: bin edges by dst bucket (packed 4B/edge) ---------
// packed = (dst&511)<<17 | src   (src < 2^17)
__global__ __launch_bounds__(256) void bin_kernel(
        const int* __restrict__ eidx, int E,
        unsigned* __restrict__ bedge, int* __restrict__ bcur) {
    __shared__ int hist[256];
    __shared__ int scanx[256];
    __shared__ int gbase[256];
    __shared__ unsigned stage[CHUNK];
    int tid = threadIdx.x;
    int base = blockIdx.x * CHUNK;
    if (base >= E) return;
    int m = min(CHUNK, E - base);
    hist[tid] = 0;
    __syncthreads();
    unsigned pk[8];
    int b[8], r[8];
#pragma unroll
    for (int j = 0; j < 8; ++j) {
        int rel = j * 256 + tid;
        bool ok = rel < m;
        int e = base + (ok ? rel : 0);
        int s = eidx[e];
        int d = eidx[E + e];
        b[j] = d >> BSHIFT;
        pk[j] = ((unsigned)(d & ((1 << BSHIFT) - 1)) << 17) | (unsigned)s;
        r[j] = ok ? atomicAdd(&hist[b[j]], 1) : -1;
    }
    __syncthreads();
    int h = hist[tid];
    scanx[tid] = h;
    __syncthreads();
    for (int st = 1; st < 256; st <<= 1) {
        int y = (tid >= st) ? scanx[tid - st] : 0;
        __syncthreads();
        scanx[tid] += y;
        __syncthreads();
    }
    int excl = scanx[tid] - h;
    if (h > 0) gbase[tid] = atomicAdd(&bcur[tid], h);
    __syncthreads();
    scanx[tid] = excl;
    __syncthreads();
#pragma unroll
    for (int j = 0; j < 8; ++j)
        if (r[j] >= 0) stage[scanx[b[j]] + r[j]] = pk[j];
    __syncthreads();
    // flush: consecutive i -> same/adjacent bin regions (coalesced-ish)
    for (int i = tid; i < m; i += 256) {
        int lo = 0, hi = NBKT - 1;
        while (lo < hi) {
            int mid = (lo + hi + 1) >> 1;
            if (scanx[mid] <= i) lo = mid; else hi = mid - 1;
        }
        int idx = gbase[lo] + (i - scanx[lo]);
        if (idx < CAPB) bedge[(size_t)lo * CAPB + idx] = stage[i];
    }
}

// ---------------- phase 2a: per-node counts from binned edges ---------------
__global__ __launch_bounds__(512) void count2_kernel(
        const unsigned* __restrict__ bedge, const int* __restrict__ bcur,
        int* __restrict__ counts, int n) {
    __shared__ int h[512];
    int b = blockIdx.x;
    int tid = threadIdx.x;
    h[tid] = 0;
    __syncthreads();
    int cnt = min(bcur[b], CAPB);
    const unsigned* e = bedge + (size_t)b * CAPB;
    for (int i = tid; i < cnt; i += 512) atomicAdd(&h[e[i] >> 17], 1);
    __syncthreads();
    int node = b * 512 + tid;
    if (node < n) counts[node] = h[tid];
}

// dis[i] = rsqrt(deg+1) for i<n; dis[n] = 0 (dummy node for pad slots)
__global__ void dis_kernel(const int* __restrict__ counts, float* __restrict__ dis, int n) {
    int i = blockIdx.x * 256 + threadIdx.x;
    if (i < n) dis[i] = rsqrtf((float)(counts[i] + 1));
    else if (i == n) dis[i] = 0.f;
}

// exclusive scan of PADDED counts -> offs; 1024 elements per block
__global__ void scan_local(const int* __restrict__ counts, int* __restrict__ offs,
                           int* __restrict__ bsums, int n) {
    __shared__ int tsum[256];
    int t = threadIdx.x;
    int base = blockIdx.x * 1024 + t * 4;
    int v0 = (base + 0 < n) ? ((counts[base + 0] + 7) & ~7) : 0;
    int v1 = (base + 1 < n) ? ((counts[base + 1] + 7) & ~7) : 0;
    int v2 = (base + 2 < n) ? ((counts[base + 2] + 7) & ~7) : 0;
    int v3 = (base + 3 < n) ? ((counts[base + 3] + 7) & ~7) : 0;
    tsum[t] = v0 + v1 + v2 + v3;
    __syncthreads();
    for (int d = 1; d < 256; d <<= 1) {
        int x = tsum[t];
        int y = (t >= d) ? tsum[t - d] : 0;
        __syncthreads();
        tsum[t] = x + y;
        __syncthreads();
    }
    int prev = (t > 0) ? tsum[t - 1] : 0;
    if (base + 0 < n) offs[base + 0] = prev;
    if (base + 1 < n) offs[base + 1] = prev + v0;
    if (base + 2 < n) offs[base + 2] = prev + v0 + v1;
    if (base + 3 < n) offs[base + 3] = prev + v0 + v1 + v2;
    if (t == 255) bsums[blockIdx.x] = tsum[255];
}

__global__ void scan_bsums(int* __restrict__ bsums, int nb) {
    __shared__ int s[128];
    int t = threadIdx.x;
    s[t] = (t < nb) ? bsums[t] : 0;
    __syncthreads();
    for (int d = 1; d < 128; d <<= 1) {
        int x = s[t];
        int y = (t >= d) ? s[t - d] : 0;
        __syncthreads();
        s[t] = x + y;
        __syncthreads();
    }
    int excl = (t > 0) ? s[t - 1] : 0;
    if (t < nb) bsums[t] = excl;
}

__global__ void add_base(int* __restrict__ offs, const int* __restrict__ bsums, int n) {
    int i = blockIdx.x * 256 + threadIdx.x;
    if (i < n) offs[i] += bsums[i >> 10];
}

// ---------------- phase 2b: bucket-local CSR fill (LDS cursors) -------------
__global__ __launch_bounds__(512) void fill2_kernel(
        const unsigned* __restrict__ bedge, const int* __restrict__ bcur,
        const int* __restrict__ offs, int* __restrict__ csrc, int n) {
    __shared__ int lofs[512];
    __shared__ int lcur[512];
    int b = blockIdx.x;
    int tid = threadIdx.x;
    int node = b * 512 + tid;
    lofs[tid] = (node < n) ? offs[node] : 0;
    lcur[tid] = 0;
    __syncthreads();
    int cnt = min(bcur[b], CAPB);
    const unsigned* e = bedge + (size_t)b * CAPB;
    for (int i = tid; i < cnt; i += 512) {
        unsigned pk = e[i];
        int dl = pk >> 17;
        int p = lofs[dl] + atomicAdd(&lcur[dl], 1);
        csrc[p] = (int)(pk & 0x1FFFFu);
    }
}

// fill pad tail of each segment with dummy node N (dis[N]=0 -> zero contribution)
__global__ void pad_kernel(const int* __restrict__ offs, const int* __restrict__ counts,
                           int* __restrict__ csrc, int n) {
    int i = blockIdx.x * 256 + threadIdx.x;
    if (i >= n) return;
    int c = counts[i];
    int p = (c + 7) & ~7;
    int o = offs[i];
    for (int j = c; j < p; ++j) csrc[o + j] = NNODES;
}

// fp32 -> fp16 cast (2 elements per thread)
__global__ void cast_kernel(const float* __restrict__ src, _Float16* __restrict__ dst, int n2) {
    int i = blockIdx.x * 256 + threadIdx.x;
    if (i < n2) {
        float2 v = *(const float2*)&src[i * 2];
        f16x2 h;
        h.x = (_Float16)v.x;
        h.y = (_Float16)v.y;
        *(f16x2*)&dst[i * 2] = h;
    }
}

// ---------------- aggregation: one wave per destination node ----------------
// out[i] = dis[i]^2 * in[i] + sum_e (dis[src]*dis[i]) * in[src[e]]
// in fp16; accumulate fp32; out fp16 (feeds MFMA GEMM A directly).

__global__ __launch_bounds__(256) void agg128_kernel(
        const f16x2* __restrict__ in, f16x2* __restrict__ out,
        const int* __restrict__ offs, const int* __restrict__ counts,
        const int* __restrict__ csrc, const float* __restrict__ dis, int n) {
    int wid = blockIdx.x * (blockDim.x >> 6) + (threadIdx.x >> 6);
    int lane = threadIdx.x & 63;
    if (wid >= n) return;
    float dd = dis[wid];
    f16x2 self = in[(size_t)wid * 64 + lane];
    float a0 = dd * dd * (float)self.x;
    float a1 = dd * dd * (float)self.y;
    int off = offs[wid];
    int pcnt = (counts[wid] + 7) & ~7;
    for (int j = 0; j < pcnt; j += 8) {
        int4 s0 = *(const int4*)&csrc[off + j];
        int4 s1 = *(const int4*)&csrc[off + j + 4];
        float v0 = dis[s0.x] * dd, v1 = dis[s0.y] * dd;
        float v2 = dis[s0.z] * dd, v3 = dis[s0.w] * dd;
        float v4 = dis[s1.x] * dd, v5 = dis[s1.y] * dd;
        float v6 = dis[s1.z] * dd, v7 = dis[s1.w] * dd;
        f16x2 r0 = in[(size_t)s0.x * 64 + lane];
        f16x2 r1 = in[(size_t)s0.y * 64 + lane];
        f16x2 r2 = in[(size_t)s0.z * 64 + lane];
        f16x2 r3 = in[(size_t)s0.w * 64 + lane];
        f16x2 r4 = in[(size_t)s1.x * 64 + lane];
        f16x2 r5 = in[(size_t)s1.y * 64 + lane];
        f16x2 r6 = in[(size_t)s1.z * 64 + lane];
        f16x2 r7 = in[(size_t)s1.w * 64 + lane];
        a0 = fmaf(v0, (float)r0.x, a0); a1 = fmaf(v0, (float)r0.y, a1);
        a0 = fmaf(v1, (float)r1.x, a0); a1 = fmaf(v1, (float)r1.y, a1);
        a0 = fmaf(v2, (float)r2.x, a0); a1 = fmaf(v2, (float)r2.y, a1);
        a0 = fmaf(v3, (float)r3.x, a0); a1 = fmaf(v3, (float)r3.y, a1);
        a0 = fmaf(v4, (float)r4.x, a0); a1 = fmaf(v4, (float)r4.y, a1);
        a0 = fmaf(v5, (float)r5.x, a0); a1 = fmaf(v5, (float)r5.y, a1);
        a0 = fmaf(v6, (float)r6.x, a0); a1 = fmaf(v6, (float)r6.y, a1);
        a0 = fmaf(v7, (float)r7.x, a0); a1 = fmaf(v7, (float)r7.y, a1);
    }
    f16x2 o;
    o.x = (_Float16)a0;
    o.y = (_Float16)a1;
    out[(size_t)wid * 64 + lane] = o;
}

// 50-dim variant: output stride 64 fp16 with zero pad (feeds K=64 MFMA GEMM)
__global__ __launch_bounds__(256) void agg50_kernel(
        const _Float16* __restrict__ in, _Float16* __restrict__ out,
        const int* __restrict__ offs, const int* __restrict__ counts,
        const int* __restrict__ csrc, const float* __restrict__ dis, int n) {
    int wid = blockIdx.x * (blockDim.x >> 6) + (threadIdx.x >> 6);
    int lane = threadIdx.x & 63;
    if (wid >= n) return;
    float dd = dis[wid];
    float acc = 0.f;
    if (lane < 50) acc = dd * dd * (float)in[(size_t)wid * 50 + lane];
    int off = offs[wid];
    int pcnt = (counts[wid] + 7) & ~7;
    for (int j = 0; j < pcnt; j += 8) {
        int4 s0 = *(const int4*)&csrc[off + j];
        int4 s1 = *(const int4*)&csrc[off + j + 4];
        float v0 = dis[s0.x] * dd, v1 = dis[s0.y] * dd;
        float v2 = dis[s0.z] * dd, v3 = dis[s0.w] * dd;
        float v4 = dis[s1.x] * dd, v5 = dis[s1.y] * dd;
        float v6 = dis[s1.z] * dd, v7 = dis[s1.w] * dd;
        if (lane < 50) {
            float r0 = (float)in[(size_t)s0.x * 50 + lane];
            float r1 = (float)in[(size_t)s0.y * 50 + lane];
            float r2 = (float)in[(size_t)s0.z * 50 + lane];
            float r3 = (float)in[(size_t)s0.w * 50 + lane];
            float r4 = (float)in[(size_t)s1.x * 50 + lane];
            float r5 = (float)in[(size_t)s1.y * 50 + lane];
            float r6 = (float)in[(size_t)s1.z * 50 + lane];
            float r7 = (float)in[(size_t)s1.w * 50 + lane];
            acc = fmaf(v0, r0, acc);
            acc = fmaf(v1, r1, acc);
            acc = fmaf(v2, r2, acc);
            acc = fmaf(v3, r3, acc);
            acc = fmaf(v4, r4, acc);
            acc = fmaf(v5, r5, acc);
            acc = fmaf(v6, r6, acc);
            acc = fmaf(v7, r7, acc);
        }
    }
    out[(size_t)wid * 64 + lane] = (lane < 50) ? (_Float16)acc : (_Float16)0.f;
}

// ---------------- W -> per-lane fragment order (fp16), once per launch ------
__global__ void wfrag_kernel(const float* __restrict__ W, f16x8* __restrict__ frag,
                             int FIN, int FOUT, int KCN, int CTN) {
    int idx = blockIdx.x * 256 + threadIdx.x;
    int tot = KCN * CTN * 64;
    if (idx >= tot) return;
    int lane = idx & 63;
    int ct = (idx >> 6) % CTN;
    int kc = (idx >> 6) / CTN;
    int c = ct * 16 + (lane & 15);
    int kb = kc * 32 + (lane >> 4) * 8;
    f16x8 v;
#pragma unroll
    for (int j = 0; j < 8; ++j) {
        int k = kb + j;
        float w = (k < FIN && c < FOUT) ? W[(size_t)k * FOUT + c] : 0.f;
        v[j] = (_Float16)w;
    }
    frag[idx] = v;
}

// ---------------- MFMA GEMM + bias + activation ----------------
// 1 wave = 16 rows x (CTN*16) cols. A fp16, W fp16 frags, fp32 accum.
// No LDS, no barriers. ACT: 0=relu, 1=sigmoid.
template <int KCN, int CTN, int ACT, typename OT>
__global__ __launch_bounds__(256) void gemm_mfma(
        const _Float16* __restrict__ A, int lda,
        const f16x8* __restrict__ wfrag,
        const float* __restrict__ bias, int fout,
        OT* __restrict__ out, int ldo, int n) {
    int wid = blockIdx.x * 4 + (threadIdx.x >> 6);
    int lane = threadIdx.x & 63;
    int rbase = wid * 16;
    if (rbase >= n) return;
    int r = lane & 15;
    int g = lane >> 4;
    int gr = rbase + r;
    const _Float16* arow = A + (size_t)((gr < n) ? gr : 0) * lda + g * 8;

    f32x4 acc[CTN];
#pragma unroll
    for (int ct = 0; ct < CTN; ++ct) acc[ct] = (f32x4){0.f, 0.f, 0.f, 0.f};

#pragma unroll
    for (int kc = 0; kc < KCN; ++kc) {
        f16x8 a = *(const f16x8*)(arow + kc * 32);
        const f16x8* wk = wfrag + (size_t)(kc * CTN) * 64 + lane;
#pragma unroll
        for (int ct = 0; ct < CTN; ++ct) {
            f16x8 b = wk[(size_t)ct * 64];
            acc[ct] = __builtin_amdgcn_mfma_f32_16x16x32_f16(a, b, acc[ct], 0, 0, 0);
        }
    }

    int orow0 = rbase + g * 4;
#pragma unroll
    for (int ct = 0; ct < CTN; ++ct) {
        int col = ct * 16 + (lane & 15);
        if (col >= fout) continue;
        float bv = bias[col];
#pragma unroll
        for (int q = 0; q < 4; ++q) {
            int orow = orow0 + q;
            if (orow >= n) continue;
            float v = acc[ct][q] + bv;
            if (ACT == 0) v = fmaxf(v, 0.f);
            else v = 1.f / (1.f + __expf(-v));
            out[(size_t)orow * ldo + col] = (OT)v;
        }
    }
}

extern "C" void kernel_launch(void* const* d_in, const int* in_sizes, int n_in,
                              void* d_out, int out_size, void* d_ws, size_t ws_size,
                              hipStream_t stream) {
    const float* x = (const float*)d_in[0];
    const int* eidx = (const int*)d_in[1];
    const float* W1 = (const float*)d_in[2];
    const float* b1 = (const float*)d_in[3];
    const float* W2 = (const float*)d_in[4];
    const float* b2 = (const float*)d_in[5];
    const float* W3 = (const float*)d_in[6];
    const float* b3 = (const float*)d_in[7];
    const float* W4 = (const float*)d_in[8];
    const float* b4 = (const float*)d_in[9];
    float* out = (float*)d_out;

    const int N = NNODES;
    const int E = in_sizes[1] / 2;
    const size_t PE = (size_t)E + 8u * N;  // padded edge-array capacity

    char* ws = (char*)d_ws;
    size_t off = 0;
    auto alloc = [&](size_t bytes) -> char* {
        char* p = ws + off;
        off = (off + bytes + 255) & ~(size_t)255;
        return p;
    };
    float* dis = (float*)alloc((size_t)(N + 1) * 4);
    int* counts = (int*)alloc((size_t)N * 4);
    int* offs = (int*)alloc((size_t)N * 4);
    int* bsums = (int*)alloc(128 * 4);
    int* bcur = (int*)alloc(256 * 4);
    int* csrc = (int*)alloc(PE * 4);
    _Float16* aggH = (_Float16*)alloc((size_t)N * 128 * 2);      // agg output (fp16)
    _Float16* hH = (_Float16*)alloc((size_t)(N + 1) * 128 * 2);  // h fp16 (gathered)
    _Float16* x16 = (_Float16*)alloc((size_t)(N + 1) * 50 * 2);  // x fp16
    f16x8* wf1 = (f16x8*)alloc((size_t)2 * 8 * 64 * 16);
    f16x8* wf2 = (f16x8*)alloc((size_t)4 * 8 * 64 * 16);
    f16x8* wf3 = (f16x8*)alloc((size_t)4 * 8 * 64 * 16);
    f16x8* wf4 = (f16x8*)alloc((size_t)4 * 8 * 64 * 16);
    // bedge aliases aggH: bedge dead before agg50 first writes aggH
    unsigned* bedge = (unsigned*)aggH;  // NBKT*CAPB*4 = ~8MB < 25.6MB

    hipMemsetAsync(bcur, 0, 256 * 4, stream);

    // weight fragments (once per launch)
    wfrag_kernel<<<(2 * 8 * 64 + 255) / 256, 256, 0, stream>>>(W1, wf1, 50, 128, 2, 8);
    wfrag_kernel<<<(4 * 8 * 64 + 255) / 256, 256, 0, stream>>>(W2, wf2, 128, 128, 4, 8);
    wfrag_kernel<<<(4 * 8 * 64 + 255) / 256, 256, 0, stream>>>(W3, wf3, 128, 128, 4, 8);
    wfrag_kernel<<<(4 * 8 * 64 + 255) / 256, 256, 0, stream>>>(W4, wf4, 128, 121, 4, 8);

    // CSR build: bin -> counts -> dis -> scan -> bucket-local fill -> pad
    bin_kernel<<<(E + CHUNK - 1) / CHUNK, 256, 0, stream>>>(eidx, E, bedge, bcur);
    count2_kernel<<<NBKT, 512, 0, stream>>>(bedge, bcur, counts, N);
    dis_kernel<<<(N + 256) / 256, 256, 0, stream>>>(counts, dis, N);
    int nb = (N + 1023) / 1024;
    scan_local<<<nb, 256, 0, stream>>>(counts, offs, bsums, N);
    scan_bsums<<<1, 128, 0, stream>>>(bsums, nb);
    add_base<<<(N + 255) / 256, 256, 0, stream>>>(offs, bsums, N);
    fill2_kernel<<<NBKT, 512, 0, stream>>>(bedge, bcur, offs, csrc, N);
    pad_kernel<<<(N + 255) / 256, 256, 0, stream>>>(offs, counts, csrc, N);

    int nx2 = N * 50 / 2;
    cast_kernel<<<(nx2 + 255) / 256, 256, 0, stream>>>(x, x16, nx2);

    int gblocks = ((N + 15) / 16 + 3) / 4;
    // layer 1: agg 50-dim (fp16 gather) -> aggH[.][64] ; MFMA GEMM 64->128 + relu -> fp16
    agg50_kernel<<<(N + 3) / 4, 256, 0, stream>>>(x16, aggH, offs, counts, csrc, dis, N);
    gemm_mfma<2, 8, 0, _Float16><<<gblocks, 256, 0, stream>>>(aggH, 64, wf1, b1, 128, hH, 128, N);
    // layer 2
    agg128_kernel<<<(N + 3) / 4, 256, 0, stream>>>((const f16x2*)hH, (f16x2*)aggH, offs, counts, csrc, dis, N);
    gemm_mfma<4, 8, 0, _Float16><<<gblocks, 256, 0, stream>>>(aggH, 128, wf2, b2, 128, hH, 128, N);
    // layer 3
    agg128_kernel<<<(N + 3) / 4, 256, 0, stream>>>((const f16x2*)hH, (f16x2*)aggH, offs, counts, csrc, dis, N);
    gemm_mfma<4, 8, 0, _Float16><<<gblocks, 256, 0, stream>>>(aggH, 128, wf3, b3, 128, hH, 128, N);
    // layer 4: agg 128 -> MFMA GEMM 128->121 + sigmoid -> fp32 d_out
    agg128_kernel<<<(N + 3) / 4, 256, 0, stream>>>((const f16x2*)hH, (f16x2*)aggH, offs, counts, csrc, dis, N);
    gemm_mfma<4, 8, 1, float><<<gblocks, 256, 0, stream>>>(aggH, 128, wf4, b4, 121, out, 121, N);
}

// Round 8
// 378.322 us; speedup vs baseline: 4.4483x; 1.1342x over previous
//
#include <hip/hip_runtime.h>
#include <math.h>

#define NNODES 100000
#define BSHIFT 9
#define NBKT ((NNODES + (1 << BSHIFT) - 1) >> BSHIFT)   // 196 buckets of 512 nodes
#define CAPB 10240                                       // expected 8163 + 23 sigma
#define CHUNK 2048

typedef _Float16 f16x8 __attribute__((ext_vector_type(8)));
typedef _Float16 f16x2 __attribute__((ext_vector_type(2)));
typedef float f32x4 __attribute__((ext_vector_type(4)));

// ---------------- phase 1: bin edges by dst bucket (packed 4B/edge) ---------
// packed = (dst&511)<<17 | src   (src < 2^17)
__global__ __launch_bounds__(256) void bin_kernel(
        const int* __restrict__ eidx, int E,
        unsigned* __restrict__ bedge, int* __restrict__ bcur) {
    __shared__ int hist[256];
    __shared__ int scanx[256];
    __shared__ int gbase[256];
    __shared__ unsigned stage[CHUNK];
    int tid = threadIdx.x;
    int base = blockIdx.x * CHUNK;
    if (base >= E) return;
    int m = min(CHUNK, E - base);
    hist[tid] = 0;
    __syncthreads();
    unsigned pk[8];
    int b[8], r[8];
#pragma unroll
    for (int j = 0; j < 8; ++j) {
        int rel = j * 256 + tid;
        bool ok = rel < m;
        int e = base + (ok ? rel : 0);
        int s = eidx[e];
        int d = eidx[E + e];
        b[j] = d >> BSHIFT;
        pk[j] = ((unsigned)(d & ((1 << BSHIFT) - 1)) << 17) | (unsigned)s;
        r[j] = ok ? atomicAdd(&hist[b[j]], 1) : -1;
    }
    __syncthreads();
    int h = hist[tid];
    scanx[tid] = h;
    __syncthreads();
    for (int st = 1; st < 256; st <<= 1) {
        int y = (tid >= st) ? scanx[tid - st] : 0;
        __syncthreads();
        scanx[tid] += y;
        __syncthreads();
    }
    int excl = scanx[tid] - h;
    if (h > 0) gbase[tid] = atomicAdd(&bcur[tid], h);
    __syncthreads();
    scanx[tid] = excl;
    __syncthreads();
#pragma unroll
    for (int j = 0; j < 8; ++j)
        if (r[j] >= 0) stage[scanx[b[j]] + r[j]] = pk[j];
    __syncthreads();
    for (int i = tid; i < m; i += 256) {
        int lo = 0, hi = NBKT - 1;
        while (lo < hi) {
            int mid = (lo + hi + 1) >> 1;
            if (scanx[mid] <= i) lo = mid; else hi = mid - 1;
        }
        int idx = gbase[lo] + (i - scanx[lo]);
        if (idx < CAPB) bedge[(size_t)lo * CAPB + idx] = stage[i];
    }
}

// ---------------- phase 2a: per-node counts from binned edges ---------------
__global__ __launch_bounds__(512) void count2_kernel(
        const unsigned* __restrict__ bedge, const int* __restrict__ bcur,
        int* __restrict__ counts, int n) {
    __shared__ int h[512];
    int b = blockIdx.x;
    int tid = threadIdx.x;
    h[tid] = 0;
    __syncthreads();
    int cnt = min(bcur[b], CAPB);
    const unsigned* e = bedge + (size_t)b * CAPB;
    for (int i = tid; i < cnt; i += 512) atomicAdd(&h[e[i] >> 17], 1);
    __syncthreads();
    int node = b * 512 + tid;
    if (node < n) counts[node] = h[tid];
}

// dis[i] = rsqrt(deg+1) for i<n; dis[n] = 0 (dummy node for pad slots)
__global__ void dis_kernel(const int* __restrict__ counts, float* __restrict__ dis, int n) {
    int i = blockIdx.x * 256 + threadIdx.x;
    if (i < n) dis[i] = rsqrtf((float)(counts[i] + 1));
    else if (i == n) dis[i] = 0.f;
}

// exclusive scan of PADDED counts -> offs; 1024 elements per block
__global__ void scan_local(const int* __restrict__ counts, int* __restrict__ offs,
                           int* __restrict__ bsums, int n) {
    __shared__ int tsum[256];
    int t = threadIdx.x;
    int base = blockIdx.x * 1024 + t * 4;
    int v0 = (base + 0 < n) ? ((counts[base + 0] + 7) & ~7) : 0;
    int v1 = (base + 1 < n) ? ((counts[base + 1] + 7) & ~7) : 0;
    int v2 = (base + 2 < n) ? ((counts[base + 2] + 7) & ~7) : 0;
    int v3 = (base + 3 < n) ? ((counts[base + 3] + 7) & ~7) : 0;
    tsum[t] = v0 + v1 + v2 + v3;
    __syncthreads();
    for (int d = 1; d < 256; d <<= 1) {
        int x = tsum[t];
        int y = (t >= d) ? tsum[t - d] : 0;
        __syncthreads();
        tsum[t] = x + y;
        __syncthreads();
    }
    int prev = (t > 0) ? tsum[t - 1] : 0;
    if (base + 0 < n) offs[base + 0] = prev;
    if (base + 1 < n) offs[base + 1] = prev + v0;
    if (base + 2 < n) offs[base + 2] = prev + v0 + v1;
    if (base + 3 < n) offs[base + 3] = prev + v0 + v1 + v2;
    if (t == 255) bsums[blockIdx.x] = tsum[255];
}

__global__ void scan_bsums(int* __restrict__ bsums, int nb) {
    __shared__ int s[128];
    int t = threadIdx.x;
    s[t] = (t < nb) ? bsums[t] : 0;
    __syncthreads();
    for (int d = 1; d < 128; d <<= 1) {
        int x = s[t];
        int y = (t >= d) ? s[t - d] : 0;
        __syncthreads();
        s[t] = x + y;
        __syncthreads();
    }
    int excl = (t > 0) ? s[t - 1] : 0;
    if (t < nb) bsums[t] = excl;
}

__global__ void add_base(int* __restrict__ offs, const int* __restrict__ bsums, int n) {
    int i = blockIdx.x * 256 + threadIdx.x;
    if (i < n) offs[i] += bsums[i >> 10];
}

// ---------------- phase 2b: bucket-local CSR fill (LDS cursors) -------------
__global__ __launch_bounds__(512) void fill2_kernel(
        const unsigned* __restrict__ bedge, const int* __restrict__ bcur,
        const int* __restrict__ offs, int* __restrict__ csrc, int n) {
    __shared__ int lofs[512];
    __shared__ int lcur[512];
    int b = blockIdx.x;
    int tid = threadIdx.x;
    int node = b * 512 + tid;
    lofs[tid] = (node < n) ? offs[node] : 0;
    lcur[tid] = 0;
    __syncthreads();
    int cnt = min(bcur[b], CAPB);
    const unsigned* e = bedge + (size_t)b * CAPB;
    for (int i = tid; i < cnt; i += 512) {
        unsigned pk = e[i];
        int dl = pk >> 17;
        int p = lofs[dl] + atomicAdd(&lcur[dl], 1);
        csrc[p] = (int)(pk & 0x1FFFFu);
    }
}

// fill pad tail of each segment with dummy node N (dis[N]=0 -> zero contribution)
__global__ void pad_kernel(const int* __restrict__ offs, const int* __restrict__ counts,
                           int* __restrict__ csrc, int n) {
    int i = blockIdx.x * 256 + threadIdx.x;
    if (i >= n) return;
    int c = counts[i];
    int p = (c + 7) & ~7;
    int o = offs[i];
    for (int j = c; j < p; ++j) csrc[o + j] = NNODES;
}

// x fp32 [N][50] -> fp16 [N][64] zero-padded (aligned gather + K=64 GEMM)
__global__ void cast_pad_kernel(const float* __restrict__ src, _Float16* __restrict__ dst,
                                int n) {
    int t = blockIdx.x * 256 + threadIdx.x;
    if (t >= n * 32) return;
    int node = t >> 5;
    int cp = t & 31;
    int c = cp * 2;
    float v0 = (c < 50) ? src[(size_t)node * 50 + c] : 0.f;
    float v1 = (c + 1 < 50) ? src[(size_t)node * 50 + c + 1] : 0.f;
    f16x2 h;
    h.x = (_Float16)v0;
    h.y = (_Float16)v1;
    *(f16x2*)&dst[(size_t)node * 64 + c] = h;
}

// ---------------- W -> per-lane fragment order (fp16), once per launch ------
__global__ void wfrag_kernel(const float* __restrict__ W, f16x8* __restrict__ frag,
                             int FIN, int FOUT, int KCN, int CTN) {
    int idx = blockIdx.x * 256 + threadIdx.x;
    int tot = KCN * CTN * 64;
    if (idx >= tot) return;
    int lane = idx & 63;
    int ct = (idx >> 6) % CTN;
    int kc = (idx >> 6) / CTN;
    int c = ct * 16 + (lane & 15);
    int kb = kc * 32 + (lane >> 4) * 8;
    f16x8 v;
#pragma unroll
    for (int j = 0; j < 8; ++j) {
        int k = kb + j;
        float w = (k < FIN && c < FOUT) ? W[(size_t)k * FOUT + c] : 0.f;
        v[j] = (_Float16)w;
    }
    frag[idx] = v;
}

// ---------------- fused aggregate + MFMA GEMM + bias + activation -----------
// Block = 16 nodes, 4 waves. Phase 1: wave aggregates 4 nodes (fp32 accum,
// fp16 round) into a 16xK LDS tile, XOR-swizzled (byte ^= (row&7)<<4).
// Phase 2: per wave KCNx2 MFMAs (16x16x32 f16) + bias/act + direct store.
// Requires n % 16 == 0. ACT: 0=relu, 1=sigmoid.
template <int KCN, int ACT, typename OT>
__global__ __launch_bounds__(256) void fused_kernel(
        const f16x2* __restrict__ in, const int* __restrict__ offs,
        const int* __restrict__ counts, const int* __restrict__ csrc,
        const float* __restrict__ dis, const f16x8* __restrict__ wfrag,
        const float* __restrict__ bias, int fout,
        OT* __restrict__ out, int ldo, int n) {
    constexpr int K = KCN * 32;
    constexpr int ROWB = K * 2;   // bytes per LDS row
    constexpr int HW = K / 2;     // f16x2 per row
    __shared__ __align__(16) unsigned char sA[16 * ROWB];
    int tid = threadIdx.x;
    int wv = tid >> 6, lane = tid & 63;
    int nb = blockIdx.x * 16;
    bool act = lane < HW;

#pragma unroll 1
    for (int s = 0; s < 4; ++s) {
        int node = nb + wv * 4 + s;
        float dd = dis[node];
        float a0 = 0.f, a1 = 0.f;
        if (act) {
            f16x2 self = in[(size_t)node * HW + lane];
            a0 = dd * dd * (float)self.x;
            a1 = dd * dd * (float)self.y;
        }
        int off = offs[node];
        int pcnt = (counts[node] + 7) & ~7;
        for (int j = 0; j < pcnt; j += 8) {
            int4 s0 = *(const int4*)&csrc[off + j];
            int4 s1 = *(const int4*)&csrc[off + j + 4];
            float v0 = dis[s0.x] * dd, v1 = dis[s0.y] * dd;
            float v2 = dis[s0.z] * dd, v3 = dis[s0.w] * dd;
            float v4 = dis[s1.x] * dd, v5 = dis[s1.y] * dd;
            float v6 = dis[s1.z] * dd, v7 = dis[s1.w] * dd;
            if (act) {
                f16x2 r0 = in[(size_t)s0.x * HW + lane];
                f16x2 r1 = in[(size_t)s0.y * HW + lane];
                f16x2 r2 = in[(size_t)s0.z * HW + lane];
                f16x2 r3 = in[(size_t)s0.w * HW + lane];
                f16x2 r4 = in[(size_t)s1.x * HW + lane];
                f16x2 r5 = in[(size_t)s1.y * HW + lane];
                f16x2 r6 = in[(size_t)s1.z * HW + lane];
                f16x2 r7 = in[(size_t)s1.w * HW + lane];
                a0 = fmaf(v0, (float)r0.x, a0); a1 = fmaf(v0, (float)r0.y, a1);
                a0 = fmaf(v1, (float)r1.x, a0); a1 = fmaf(v1, (float)r1.y, a1);
                a0 = fmaf(v2, (float)r2.x, a0); a1 = fmaf(v2, (float)r2.y, a1);
                a0 = fmaf(v3, (float)r3.x, a0); a1 = fmaf(v3, (float)r3.y, a1);
                a0 = fmaf(v4, (float)r4.x, a0); a1 = fmaf(v4, (float)r4.y, a1);
                a0 = fmaf(v5, (float)r5.x, a0); a1 = fmaf(v5, (float)r5.y, a1);
                a0 = fmaf(v6, (float)r6.x, a0); a1 = fmaf(v6, (float)r6.y, a1);
                a0 = fmaf(v7, (float)r7.x, a0); a1 = fmaf(v7, (float)r7.y, a1);
            }
        }
        int r = wv * 4 + s;
        if (act) {
            f16x2 o;
            o.x = (_Float16)a0;
            o.y = (_Float16)a1;
            *(f16x2*)(sA + r * ROWB + ((lane * 4) ^ ((r & 7) << 4))) = o;
        }
    }
    __syncthreads();

    // ---- phase 2: GEMM ----
    int r = lane & 15, g = lane >> 4;
    f32x4 acc[2];
    acc[0] = (f32x4){0.f, 0.f, 0.f, 0.f};
    acc[1] = (f32x4){0.f, 0.f, 0.f, 0.f};
#pragma unroll
    for (int kc = 0; kc < KCN; ++kc) {
        f16x8 a = *(const f16x8*)(sA + r * ROWB + ((kc * 64 + g * 16) ^ ((r & 7) << 4)));
        f16x8 b0 = wfrag[(size_t)(kc * 8 + wv * 2 + 0) * 64 + lane];
        f16x8 b1 = wfrag[(size_t)(kc * 8 + wv * 2 + 1) * 64 + lane];
        acc[0] = __builtin_amdgcn_mfma_f32_16x16x32_f16(a, b0, acc[0], 0, 0, 0);
        acc[1] = __builtin_amdgcn_mfma_f32_16x16x32_f16(a, b1, acc[1], 0, 0, 0);
    }
#pragma unroll
    for (int c = 0; c < 2; ++c) {
        int col = (wv * 2 + c) * 16 + r;
        if (col >= fout) continue;
        float bv = bias[col];
#pragma unroll
        for (int q = 0; q < 4; ++q) {
            int orow = nb + g * 4 + q;
            float v = acc[c][q] + bv;
            if (ACT == 0) v = fmaxf(v, 0.f);
            else v = 1.f / (1.f + __expf(-v));
            out[(size_t)orow * ldo + col] = (OT)v;
        }
    }
}

extern "C" void kernel_launch(void* const* d_in, const int* in_sizes, int n_in,
                              void* d_out, int out_size, void* d_ws, size_t ws_size,
                              hipStream_t stream) {
    const float* x = (const float*)d_in[0];
    const int* eidx = (const int*)d_in[1];
    const float* W1 = (const float*)d_in[2];
    const float* b1 = (const float*)d_in[3];
    const float* W2 = (const float*)d_in[4];
    const float* b2 = (const float*)d_in[5];
    const float* W3 = (const float*)d_in[6];
    const float* b3 = (const float*)d_in[7];
    const float* W4 = (const float*)d_in[8];
    const float* b4 = (const float*)d_in[9];
    float* out = (float*)d_out;

    const int N = NNODES;
    const int E = in_sizes[1] / 2;
    const size_t PE = (size_t)E + 8u * N;

    char* ws = (char*)d_ws;
    size_t off = 0;
    auto alloc = [&](size_t bytes) -> char* {
        char* p = ws + off;
        off = (off + bytes + 255) & ~(size_t)255;
        return p;
    };
    float* dis = (float*)alloc((size_t)(N + 1) * 4);
    int* counts = (int*)alloc((size_t)N * 4);
    int* offs = (int*)alloc((size_t)N * 4);
    int* bsums = (int*)alloc(128 * 4);
    int* bcur = (int*)alloc(256 * 4);
    int* csrc = (int*)alloc(PE * 4);
    _Float16* hA = (_Float16*)alloc((size_t)(N + 1) * 128 * 2);
    _Float16* hB = (_Float16*)alloc((size_t)(N + 1) * 128 * 2);
    _Float16* x16 = (_Float16*)alloc((size_t)(N + 1) * 64 * 2);
    f16x8* wf1 = (f16x8*)alloc((size_t)2 * 8 * 64 * 16);
    f16x8* wf2 = (f16x8*)alloc((size_t)4 * 8 * 64 * 16);
    f16x8* wf3 = (f16x8*)alloc((size_t)4 * 8 * 64 * 16);
    f16x8* wf4 = (f16x8*)alloc((size_t)4 * 8 * 64 * 16);
    // bedge aliases hB: bedge is dead before layer 2 first writes hB
    unsigned* bedge = (unsigned*)hB;  // NBKT*CAPB*4 ~= 8MB < 25.6MB

    hipMemsetAsync(bcur, 0, 256 * 4, stream);

    // weight fragments (once per launch)
    wfrag_kernel<<<(2 * 8 * 64 + 255) / 256, 256, 0, stream>>>(W1, wf1, 50, 128, 2, 8);
    wfrag_kernel<<<(4 * 8 * 64 + 255) / 256, 256, 0, stream>>>(W2, wf2, 128, 128, 4, 8);
    wfrag_kernel<<<(4 * 8 * 64 + 255) / 256, 256, 0, stream>>>(W3, wf3, 128, 128, 4, 8);
    wfrag_kernel<<<(4 * 8 * 64 + 255) / 256, 256, 0, stream>>>(W4, wf4, 128, 121, 4, 8);

    // CSR build
    bin_kernel<<<(E + CHUNK - 1) / CHUNK, 256, 0, stream>>>(eidx, E, bedge, bcur);
    count2_kernel<<<NBKT, 512, 0, stream>>>(bedge, bcur, counts, N);
    dis_kernel<<<(N + 256) / 256, 256, 0, stream>>>(counts, dis, N);
    int nb = (N + 1023) / 1024;
    scan_local<<<nb, 256, 0, stream>>>(counts, offs, bsums, N);
    scan_bsums<<<1, 128, 0, stream>>>(bsums, nb);
    add_base<<<(N + 255) / 256, 256, 0, stream>>>(offs, bsums, N);
    fill2_kernel<<<NBKT, 512, 0, stream>>>(bedge, bcur, offs, csrc, N);
    pad_kernel<<<(N + 255) / 256, 256, 0, stream>>>(offs, counts, csrc, N);

    cast_pad_kernel<<<(N * 32 + 255) / 256, 256, 0, stream>>>(x, x16, N);

    int fblocks = N / 16;  // N % 16 == 0
    // layer 1: fused agg(50->64-pad) + GEMM 64->128 + relu -> hA
    fused_kernel<2, 0, _Float16><<<fblocks, 256, 0, stream>>>(
        (const f16x2*)x16, offs, counts, csrc, dis, wf1, b1, 128, hA, 128, N);
    // layer 2: hA -> hB
    fused_kernel<4, 0, _Float16><<<fblocks, 256, 0, stream>>>(
        (const f16x2*)hA, offs, counts, csrc, dis, wf2, b2, 128, hB, 128, N);
    // layer 3: hB -> hA
    fused_kernel<4, 0, _Float16><<<fblocks, 256, 0, stream>>>(
        (const f16x2*)hB, offs, counts, csrc, dis, wf3, b3, 128, hA, 128, N);
    // layer 4: hA -> d_out (sigmoid, fp32, 121 cols)
    fused_kernel<4, 1, float><<<fblocks, 256, 0, stream>>>(
        (const f16x2*)hA, offs, counts, csrc, dis, wf4, b4, 121, out, 121, N);
}